// Round 12
// baseline (128.049 us; speedup 1.0000x reference)
//
#include <hip/hip_runtime.h>
#include <stdint.h>

// ---------------------------------------------------------------------------
// CausalSelfAttention (B=2, T=2048, D=1024, H=16, Dh=64), fp32 in/out.
// cvt (cvt_pk, Wq pre-scaled) -> fused {Q,K proj + V^T} gemm (dbuf, 1 barrier
// per K-step) -> flash attn KV-split (256-key chunks, single-buffer, setprio)
// -> merge -> out gemm.
// ---------------------------------------------------------------------------

typedef unsigned short u16;
typedef __attribute__((ext_vector_type(8)))  __bf16 bf16x8;   // 4 VGPR MFMA A/B frag
typedef __attribute__((ext_vector_type(4)))  float  f32x4;    // 16x16 C/D frag
typedef __attribute__((ext_vector_type(16))) float  f32x16;   // 32x32 C/D frag
typedef __attribute__((ext_vector_type(4)))  float  float4v;
typedef __attribute__((ext_vector_type(4)))  unsigned short u16x4;
typedef __attribute__((ext_vector_type(4)))  unsigned int   u32x4;
typedef __attribute__((ext_vector_type(8)))  short  short8;   // raw 16B load

#define BB 2
#define TT 2048
#define DD 1024
#define HH 16
#define DH 64
#define MM (BB*TT)          // 4096 rows
#define NSLOT 2304          // 32 bh * 72 (qi,chunk) slots (256-key chunks)
#define CEXP 0.18033688011f // 0.125 * log2(e), folded into Wq/bq
#define XNE ((size_t)MM*DD)
#define WNE ((size_t)DD*DD)

static __device__ __forceinline__ u16 f2bf(float f) {
    uint32_t u = __builtin_bit_cast(uint32_t, f);
    u += 0x7FFFu + ((u >> 16) & 1u);          // round-to-nearest-even
    return (u16)(u >> 16);
}
static __device__ __forceinline__ float bf2f(u16 v) {
    uint32_t u = (uint32_t)v << 16;
    return __builtin_bit_cast(float, u);
}

static __device__ __forceinline__ unsigned cvt_pk_bf16(float a, float b) {
    unsigned r;
    asm("v_cvt_pk_bf16_f32 %0, %1, %2" : "=v"(r) : "v"(a), "v"(b));
    return r;
}

// global(16B per lane) -> LDS direct copy (wave-uniform dst base + lane*16).
static __device__ __forceinline__ void load_lds16(const u16* g, const u16* lds_base) {
    __builtin_amdgcn_global_load_lds(
        (const __attribute__((address_space(1))) void*)(uintptr_t)g,
        (__attribute__((address_space(3)))  void*)(uint32_t)(uintptr_t)lds_base,
        16u, 0, 0u);
}

static __device__ __forceinline__ f32x4 mfma16(bf16x8 a, bf16x8 b, f32x4 c) {
    return __builtin_amdgcn_mfma_f32_16x16x32_bf16(a, b, c, 0, 0, 0);
}
static __device__ __forceinline__ f32x16 mfma32(bf16x8 a, bf16x8 b, f32x16 c) {
    return __builtin_amdgcn_mfma_f32_32x32x16_bf16(a, b, c, 0, 0, 0);
}

// sum of all 16 regs (15-add tree)
static __device__ __forceinline__ float tree_sum16(const f32x16& a) {
    float m[8];
#pragma unroll
    for (int r = 0; r < 8; ++r) m[r] = a[r] + a[r + 8];
#pragma unroll
    for (int off = 4; off; off >>= 1)
#pragma unroll
        for (int r = 0; r < off; ++r) m[r] += m[r + off];
    return m[0];
}

// P regs (8 f32, C-layout key groups) -> one B-operand bf16x8 (T12)
static __device__ __forceinline__ bf16x8 pack8(float s0, float s1, float s2,
        float s3, float s4, float s5, float s6, float s7) {
    unsigned c0 = cvt_pk_bf16(s0, s1);
    unsigned c1 = cvt_pk_bf16(s2, s3);
    unsigned c2 = cvt_pk_bf16(s4, s5);
    unsigned c3 = cvt_pk_bf16(s6, s7);
    asm volatile("v_permlane32_swap_b32 %0, %1" : "+v"(c0), "+v"(c2));
    asm volatile("v_permlane32_swap_b32 %0, %1" : "+v"(c1), "+v"(c3));
    u32x4 w; w[0] = c0; w[1] = c1; w[2] = c2; w[3] = c3;
    return __builtin_bit_cast(bf16x8, w);
}

// ---------------------- fp32 -> bf16 (v_cvt_pk packed) ---------------------
__global__ __launch_bounds__(256) void cvt_kernel(const float* __restrict__ src,
                                                  u16* __restrict__ dst, int n8) {
    int i = blockIdx.x * blockDim.x + threadIdx.x;
    int stride = gridDim.x * blockDim.x;
    for (; i < n8; i += stride) {
        float4v a = ((const float4v*)src)[2 * i];
        float4v b = ((const float4v*)src)[2 * i + 1];
        u32x4 o;
        o[0] = cvt_pk_bf16(a[0], a[1]); o[1] = cvt_pk_bf16(a[2], a[3]);
        o[2] = cvt_pk_bf16(b[0], b[1]); o[3] = cvt_pk_bf16(b[2], b[3]);
        ((u32x4*)dst)[i] = o;
    }
}

// four matrices in one launch; z==0 (Wq) pre-scaled by CEXP
__global__ __launch_bounds__(256) void cvt4_kernel(const float* __restrict__ s0,
        const float* __restrict__ s1, const float* __restrict__ s2,
        const float* __restrict__ s3, u16* __restrict__ d0, u16* __restrict__ d1,
        u16* __restrict__ d2, u16* __restrict__ d3, int n8) {
    const int z = blockIdx.y;
    const float* src = (z == 0) ? s0 : (z == 1) ? s1 : (z == 2) ? s2 : s3;
    u16* dst = (z == 0) ? d0 : (z == 1) ? d1 : (z == 2) ? d2 : d3;
    const float sc = (z == 0) ? CEXP : 1.0f;
    int i = blockIdx.x * blockDim.x + threadIdx.x;
    int stride = gridDim.x * blockDim.x;
    for (; i < n8; i += stride) {
        float4v a = ((const float4v*)src)[2 * i];
        float4v b = ((const float4v*)src)[2 * i + 1];
        u32x4 o;
        o[0] = cvt_pk_bf16(a[0] * sc, a[1] * sc);
        o[1] = cvt_pk_bf16(a[2] * sc, a[3] * sc);
        o[2] = cvt_pk_bf16(b[0] * sc, b[1] * sc);
        o[3] = cvt_pk_bf16(b[2] * sc, b[3] * sc);
        ((u32x4*)dst)[i] = o;
    }
}

// ----------------- GEMM, dbuf + single barrier per K-step ------------------
// 128x128 tile, BK=32, K=1024, 256 thr (4 waves 2x2). Stage(next) issued
// BEFORE compute(cur); one __syncthreads per K-step.
// MODE 0 (fused, grid 768): id<512 -> z=id>>8 Q/K proj (col-bias, bf16 out,
//   Wq path pre-scaled); id>=512 -> V^T gemm: C = Wv . x_b^T (row-bias bv),
//   out row-major [1024 hd][2048 t] at vt + b*1024*2048 (coalesced in t).
// MODE 1 (grid 256): out-proj, f32 out + col-bias.
template<int MODE>
__global__ __launch_bounds__(256) void gemm2(const u16* __restrict__ xb,
        const u16* __restrict__ Wb, const float* __restrict__ bq,
        const float* __restrict__ bk, const float* __restrict__ bvv,
        u16* __restrict__ outq, u16* __restrict__ vt, float* __restrict__ outf) {
    __shared__ alignas(16) u16 As[2][128 * 32];
    __shared__ alignas(16) u16 Bs[2][128 * 32];

    const int tid  = threadIdx.x;
    const int wave = tid >> 6, lane = tid & 63;
    const int lr = lane & 15, lg = lane >> 4;
    const int wr = wave >> 1, wc = wave & 1;
    const int K = 1024;

    const u16 *Ap, *Wp;
    int m0, n0, zb = 0;
    bool vtmode = false;
    const int id = blockIdx.x;
    if (MODE == 0) {
        if (id < 512) {
            zb = id >> 8; int r = id & 255;
            m0 = (r >> 3) * 128; n0 = (r & 7) * 128;
            Ap = xb; Wp = Wb + (size_t)zb * WNE;
        } else {
            int v = id - 512; zb = v >> 7; int r = v & 127;
            m0 = (r >> 4) * 128; n0 = (r & 15) * 128;
            Ap = Wb + 2 * WNE;                       // Wv
            Wp = xb + (size_t)zb * 2048 * 1024;      // x_b
            vtmode = true;
        }
    } else {
        m0 = (id >> 3) * 128; n0 = (id & 7) * 128;
        Ap = xb; Wp = Wb;
    }

    f32x4 acc[4][4];
#pragma unroll
    for (int m = 0; m < 4; ++m)
#pragma unroll
        for (int n = 0; n < 4; ++n) acc[m][n] = (f32x4){0.f, 0.f, 0.f, 0.f};

#define G_STAGE(BB_, KK_)                                                     \
    {                                                                         \
        _Pragma("unroll")                                                     \
        for (int it = 0; it < 2; ++it) {                                      \
            int c = it * 256 + tid;                                           \
            int row = c >> 2, cc = (c & 3) * 8;                               \
            load_lds16(Ap + (size_t)(m0 + row) * K + (KK_) + cc,              \
                       &As[BB_][(size_t)(it * 256 + wave * 64) * 8]);         \
            load_lds16(Wp + (size_t)(n0 + row) * K + (KK_) + cc,              \
                       &Bs[BB_][(size_t)(it * 256 + wave * 64) * 8]);         \
        }                                                                     \
    }

    G_STAGE(0, 0);
    __syncthreads();
    int cur = 0;
    for (int k0 = 0; k0 < K; k0 += 32) {
        if (k0 + 32 < K) G_STAGE(cur ^ 1, k0 + 32);

        bf16x8 af[4], bfm[4];
#pragma unroll
        for (int m = 0; m < 4; ++m)
            af[m] = *(const bf16x8*)&As[cur][(wr * 64 + m * 16 + lr) * 32 + lg * 8];
#pragma unroll
        for (int n = 0; n < 4; ++n)
            bfm[n] = *(const bf16x8*)&Bs[cur][(wc * 64 + n * 16 + lr) * 32 + lg * 8];
#pragma unroll
        for (int m = 0; m < 4; ++m)
#pragma unroll
            for (int n = 0; n < 4; ++n)
                acc[m][n] = mfma16(af[m], bfm[n], acc[m][n]);

        __syncthreads();   // drains vmcnt: next buffer published
        cur ^= 1;
    }
#undef G_STAGE

    if (MODE == 1) {
#pragma unroll
        for (int n = 0; n < 4; ++n) {
            int col = n0 + wc * 64 + n * 16 + lr;
            float bvl = bq[col];
#pragma unroll
            for (int m = 0; m < 4; ++m) {
                int row = m0 + wr * 64 + m * 16 + lg * 4;
#pragma unroll
                for (int r = 0; r < 4; ++r)
                    outf[(size_t)(row + r) * 1024 + col] = acc[m][n][r] + bvl;
            }
        }
    } else if (!vtmode) {
        const float* bias = zb ? bk : bq;
        const float bsc = zb ? 1.0f : CEXP;
#pragma unroll
        for (int n = 0; n < 4; ++n) {
            int col = n0 + wc * 64 + n * 16 + lr;
            float bvl = bias[col] * bsc;
#pragma unroll
            for (int m = 0; m < 4; ++m) {
                int row = m0 + wr * 64 + m * 16 + lg * 4;
#pragma unroll
                for (int r = 0; r < 4; ++r)
                    outq[(size_t)zb * XNE + (size_t)(row + r) * 1024 + col] =
                        f2bf(acc[m][n][r] + bvl);
            }
        }
    } else {
        // V^T: rows = hd (row-bias), cols = t (coalesced)
        u16* vo = vt + (size_t)zb * 1024 * 2048;
#pragma unroll
        for (int m = 0; m < 4; ++m) {
            int rowb = m0 + wr * 64 + m * 16 + lg * 4;
            float bvr[4];
#pragma unroll
            for (int r = 0; r < 4; ++r) bvr[r] = bvv[rowb + r];
#pragma unroll
            for (int n = 0; n < 4; ++n) {
                int col = n0 + wc * 64 + n * 16 + lr;
#pragma unroll
                for (int r = 0; r < 4; ++r)
                    vo[(size_t)(rowb + r) * 2048 + col] = f2bf(acc[m][n][r] + bvr[r]);
            }
        }
    }
}

// --------------------------- attention pass 1 ------------------------------
// KV-split flash partials, base-free exp2 softmax (Q pre-scaled by CEXP).
// 256-key chunks: slot s -> (qi, ch) with nch(qi) = (qi+2)>>1 (72 slots/bh).
// Grid 2304 XCD-mapped: i -> bh=(i&7)*4+(i>>3)/72, s=(i>>3)%72.
// Single-buffered K/V (16KB LDS, ~9 blocks/CU); K and V^T staged via
// global_load_lds (V pre-transposed by the GEMM). setprio(1) around MFMA
// clusters (T5). nc==1 (qi<2): normalize + write Y; else partials Op/Ml.
__global__ __launch_bounds__(256) void attn_part(const u16* __restrict__ Qb,
        const u16* __restrict__ Kb, const u16* __restrict__ VTb,
        u16* __restrict__ Op, float* __restrict__ Ml, u16* __restrict__ Yb) {
    __shared__ alignas(16) u16 Ks[64 * 64];   // [key][d], XOR-swizzled 16B slots
    __shared__ alignas(16) u16 Vs[64 * 64];   // [d][key], XOR-swizzled 16B slots

    const int tid  = threadIdx.x;
    const int wave = tid >> 6, lane = tid & 63;
    const int lq = lane & 31, hi = lane >> 5;

    const int i0 = blockIdx.x;
    const int bh = (i0 & 7) * 4 + ((i0 >> 3) / 72);
    const int s  = (i0 >> 3) % 72;
    int qi = 0, ch = 0;
    {
        int cum = 0, found = 0;
#pragma unroll
        for (int j = 0; j < 16; ++j) {
            int n = (j + 2) >> 1;
            if (!found && s < cum + n) { qi = j; ch = s - cum; found = 1; }
            cum += n;
        }
    }
    const int nc = (qi + 2) >> 1;
    const int b = bh >> 4, h = bh & 15;
    const size_t rb = (size_t)b * TT;
    const int hoff = h * DH;
    const int q0w = qi * 128 + wave * 32;     // warp q base
    const int k0 = ch * 256;
    const int kend = qi * 128 + 128;
    const int k1 = (k0 + 256 < kend) ? k0 + 256 : kend;

    // staging coords: chunk c = it*256+tid -> row=c>>3, slot=c&7
    const int srow0 = tid >> 3, sl = tid & 7;
    const int srow1 = (256 + tid) >> 3;

    const u16* Kbh = Kb + rb * DD + hoff;
    const u16* Vbh = VTb + (size_t)bh * 64 * 2048;

    // Q fragments (B-operand): col=lane&31=q, k=(lane>>5)*8+j ; 4 chunks of 16
    bf16x8 qf[4];
    {
        const u16* qrow = Qb + (rb + q0w + lq) * DD + hoff + hi * 8;
#pragma unroll
        for (int kc = 0; kc < 4; ++kc) qf[kc] = *(const bf16x8*)(qrow + kc * 16);
    }

    f32x16 o0 = {}, o1 = {};
    float l_i = 0.f;

    for (int kv0 = k0; kv0 < k1; kv0 += 64) {
        __syncthreads();
        // K tile [64 key][64 d] and V^T tile [64 d][64 key], swizzled source
        load_lds16(Kbh + (size_t)(kv0 + srow0) * DD + (sl ^ (srow0 & 7)) * 8,
                   &Ks[(size_t)(wave * 64) * 8]);
        load_lds16(Kbh + (size_t)(kv0 + srow1) * DD + (sl ^ (srow1 & 7)) * 8,
                   &Ks[(size_t)(256 + wave * 64) * 8]);
        load_lds16(Vbh + (size_t)srow0 * 2048 + kv0 + (sl ^ (srow0 & 7)) * 8,
                   &Vs[(size_t)(wave * 64) * 8]);
        load_lds16(Vbh + (size_t)srow1 * 2048 + kv0 + (sl ^ (srow1 & 7)) * 8,
                   &Vs[(size_t)(256 + wave * 64) * 8]);
        __syncthreads();

        if (kv0 < q0w + 32) {
            const int rowm = lq & 7;
            const bool diag = (kv0 + 63 > q0w);
            const int qrel = q0w + lq - kv0;
            bf16x8 pb[4];

            // ---- keys 0..31
            {
                f32x16 st = {};
                __builtin_amdgcn_s_setprio(1);
#pragma unroll
                for (int kc = 0; kc < 4; ++kc) {
                    bf16x8 kf = *(const bf16x8*)&Ks[lq * 64 + ((2 * kc + hi) ^ rowm) * 8];
                    st = mfma32(kf, qf[kc], st);
                }
                __builtin_amdgcn_s_setprio(0);
                if (diag) {
#pragma unroll
                    for (int r = 0; r < 16; ++r) {
                        int key = (r & 3) + 8 * (r >> 2) + 4 * hi;
                        if (key > qrel) st[r] = -1e30f;
                    }
                }
#pragma unroll
                for (int r = 0; r < 16; ++r) st[r] = __builtin_amdgcn_exp2f(st[r]);
                l_i += tree_sum16(st);
                pb[0] = pack8(st[0], st[1], st[2], st[3], st[4], st[5], st[6], st[7]);
                pb[1] = pack8(st[8], st[9], st[10], st[11], st[12], st[13], st[14], st[15]);
            }
            // ---- keys 32..63
            {
                f32x16 st = {};
                __builtin_amdgcn_s_setprio(1);
#pragma unroll
                for (int kc = 0; kc < 4; ++kc) {
                    bf16x8 kf = *(const bf16x8*)&Ks[(32 + lq) * 64 + ((2 * kc + hi) ^ rowm) * 8];
                    st = mfma32(kf, qf[kc], st);
                }
                __builtin_amdgcn_s_setprio(0);
                if (diag) {
#pragma unroll
                    for (int r = 0; r < 16; ++r) {
                        int key = 32 + (r & 3) + 8 * (r >> 2) + 4 * hi;
                        if (key > qrel) st[r] = -1e30f;
                    }
                }
#pragma unroll
                for (int r = 0; r < 16; ++r) st[r] = __builtin_amdgcn_exp2f(st[r]);
                l_i += tree_sum16(st);
                pb[2] = pack8(st[0], st[1], st[2], st[3], st[4], st[5], st[6], st[7]);
                pb[3] = pack8(st[8], st[9], st[10], st[11], st[12], st[13], st[14], st[15]);
            }

            // O^T += V^T . P^T : A=V^T (row=d, swizzled read), B=P^T (col=q)
            __builtin_amdgcn_s_setprio(1);
#pragma unroll
            for (int ks = 0; ks < 4; ++ks) {
                bf16x8 vf0 = *(const bf16x8*)&Vs[lq * 64        + ((ks * 2 + hi) ^ rowm) * 8];
                bf16x8 vf1 = *(const bf16x8*)&Vs[(32 + lq) * 64 + ((ks * 2 + hi) ^ rowm) * 8];
                o0 = mfma32(vf0, pb[ks], o0);
                o1 = mfma32(vf1, pb[ks], o1);
            }
            __builtin_amdgcn_s_setprio(0);
        }
    }

    l_i += __shfl_xor(l_i, 32);
    const int col = wave * 32 + lq;

    if (nc == 1) {
        // single chunk: normalize and write Y directly
        const float inv = 1.0f / l_i;
        u16* yrow = Yb + (rb + q0w + lq) * DD + hoff;
#pragma unroll
        for (int g = 0; g < 4; ++g) {
            u16x4 p0, p1;
#pragma unroll
            for (int j = 0; j < 4; ++j) {
                p0[j] = f2bf(o0[4 * g + j] * inv);
                p1[j] = f2bf(o1[4 * g + j] * inv);
            }
            *(u16x4*)&yrow[8 * g + 4 * hi]      = p0;
            *(u16x4*)&yrow[32 + 8 * g + 4 * hi] = p1;
        }
    } else {
        const int slot = bh * 72 + s;
        u16* op = Op + (size_t)slot * 8192;
#pragma unroll
        for (int r = 0; r < 16; ++r) {
            const int d0 = (r & 3) + 8 * (r >> 2) + 4 * hi;
            op[d0 * 128 + col]        = f2bf(o0[r]);
            op[(32 + d0) * 128 + col] = f2bf(o1[r]);
        }
        if (hi == 0) Ml[(size_t)slot * 128 + col] = l_i;
    }
}

// --------------------------- attention pass 2 ------------------------------
// grid 512 = 32 bh x 16 qi; 256 thr. qi<2 handled by pass1 (early return).
// O = sum_c O_c / sum_c l_c (common exp2 base, no max bookkeeping).
__global__ __launch_bounds__(256) void attn_merge(const u16* __restrict__ Op,
        const float* __restrict__ Ml, u16* __restrict__ Yb) {
    const int bq = blockIdx.x;
    const int bh = bq >> 4, qi = bq & 15;
    const int nc = (qi + 2) >> 1;
    if (nc == 1) return;
    int cum = 0;
#pragma unroll
    for (int j = 0; j < 16; ++j) cum += (j < qi) ? ((j + 2) >> 1) : 0;
    const int s0 = bh * 72 + cum;

    const int t = threadIdx.x;
    const int row = t >> 1, dh = (t & 1) * 32;

    float L = 0.f;
    float acc[32];
#pragma unroll
    for (int d = 0; d < 32; ++d) acc[d] = 0.f;
#pragma unroll
    for (int c = 0; c < 8; ++c) {
        if (c < nc) {
            L += Ml[(size_t)(s0 + c) * 128 + row];
            const u16* op = Op + (size_t)(s0 + c) * 8192 + row;
#pragma unroll
            for (int d = 0; d < 32; ++d)
                acc[d] += bf2f(op[(dh + d) * 128]);
        }
    }
    const float inv = 1.0f / L;

    const int b = bh >> 4, h = bh & 15;
    u16* yrow = Yb + ((size_t)(b * TT + qi * 128 + row)) * DD + h * DH + dh;
#pragma unroll
    for (int g = 0; g < 8; ++g) {
        u16x4 p;
#pragma unroll
        for (int j = 0; j < 4; ++j) p[j] = f2bf(acc[4 * g + j] * inv);
        *(u16x4*)&yrow[4 * g] = p;
    }
}

// ------------------------------- launcher ----------------------------------
extern "C" void kernel_launch(void* const* d_in, const int* in_sizes, int n_in,
                              void* d_out, int out_size, void* d_ws, size_t ws_size,
                              hipStream_t stream) {
    const float* x  = (const float*)d_in[0];
    const float* Wq = (const float*)d_in[1];
    const float* bq = (const float*)d_in[2];
    const float* Wk = (const float*)d_in[3];
    const float* bk = (const float*)d_in[4];
    const float* Wv = (const float*)d_in[5];
    const float* bv = (const float*)d_in[6];
    const float* Wo = (const float*)d_in[7];
    const float* bo = (const float*)d_in[8];
    float* out = (float*)d_out;

    u16* xb  = (u16*)d_ws;
    u16* Wb  = xb  + XNE;         // Wq,Wk,Wv stacked: 3*WNE
    u16* Wob = Wb  + 3 * WNE;
    u16* QKV = Wob + WNE;         // Q, K, VT stacked: 3*XNE
    u16* Yb  = QKV + 3 * XNE;
    u16* Op  = Yb  + XNE;                             // bf16 [2304][64][128]
    float* Ml = (float*)(Op + (size_t)NSLOT * 8192);  // f32 [2304][128]

    cvt_kernel<<<1024, 256, 0, stream>>>(x, xb, (int)(XNE / 8));
    cvt4_kernel<<<dim3(128, 4), 256, 0, stream>>>(Wq, Wk, Wv, Wo,
            Wb, Wb + WNE, Wb + 2 * WNE, Wob, (int)(WNE / 8));

    // fused Q-proj, K-proj, V^T gemm (768 blocks)
    gemm2<0><<<768, 256, 0, stream>>>(xb, Wb, bq, bk, bv,
                                      QKV, QKV + 2 * XNE, nullptr);
    attn_part<<<NSLOT, 256, 0, stream>>>(QKV, QKV + XNE, QKV + 2 * XNE,
                                         Op, Ml, Yb);
    attn_merge<<<512, 256, 0, stream>>>(Op, Ml, Yb);
    // out-proj (f32 out + bias)
    gemm2<1><<<256, 256, 0, stream>>>(Yb, Wob, bo, nullptr, nullptr,
                                      nullptr, nullptr, out);
}

// Round 13
// 116.318 us; speedup vs baseline: 1.1009x; 1.1009x over previous
//
#include <hip/hip_runtime.h>
#include <stdint.h>

// ---------------------------------------------------------------------------
// CausalSelfAttention (B=2, T=2048, D=1024, H=16, Dh=64), fp32 in/out.
// cvt (cvt_pk, Wq pre-scaled) -> fused {Q,K proj + V^T} gemm (dbuf, 1 barrier
// per K-step) -> flash attn KV-split (512-key chunks, single-buffer, NO
// setprio) -> merge -> out gemm.
// ---------------------------------------------------------------------------

typedef unsigned short u16;
typedef __attribute__((ext_vector_type(8)))  __bf16 bf16x8;   // 4 VGPR MFMA A/B frag
typedef __attribute__((ext_vector_type(4)))  float  f32x4;    // 16x16 C/D frag
typedef __attribute__((ext_vector_type(16))) float  f32x16;   // 32x32 C/D frag
typedef __attribute__((ext_vector_type(4)))  float  float4v;
typedef __attribute__((ext_vector_type(4)))  unsigned short u16x4;
typedef __attribute__((ext_vector_type(4)))  unsigned int   u32x4;
typedef __attribute__((ext_vector_type(8)))  short  short8;   // raw 16B load

#define BB 2
#define TT 2048
#define DD 1024
#define HH 16
#define DH 64
#define MM (BB*TT)          // 4096 rows
#define NSLOT 1280          // 32 bh * 40 (qi,chunk) slots (512-key chunks)
#define CEXP 0.18033688011f // 0.125 * log2(e), folded into Wq/bq
#define XNE ((size_t)MM*DD)
#define WNE ((size_t)DD*DD)

static __device__ __forceinline__ u16 f2bf(float f) {
    uint32_t u = __builtin_bit_cast(uint32_t, f);
    u += 0x7FFFu + ((u >> 16) & 1u);          // round-to-nearest-even
    return (u16)(u >> 16);
}
static __device__ __forceinline__ float bf2f(u16 v) {
    uint32_t u = (uint32_t)v << 16;
    return __builtin_bit_cast(float, u);
}

static __device__ __forceinline__ unsigned cvt_pk_bf16(float a, float b) {
    unsigned r;
    asm("v_cvt_pk_bf16_f32 %0, %1, %2" : "=v"(r) : "v"(a), "v"(b));
    return r;
}

// global(16B per lane) -> LDS direct copy (wave-uniform dst base + lane*16).
static __device__ __forceinline__ void load_lds16(const u16* g, const u16* lds_base) {
    __builtin_amdgcn_global_load_lds(
        (const __attribute__((address_space(1))) void*)(uintptr_t)g,
        (__attribute__((address_space(3)))  void*)(uint32_t)(uintptr_t)lds_base,
        16u, 0, 0u);
}

static __device__ __forceinline__ f32x4 mfma16(bf16x8 a, bf16x8 b, f32x4 c) {
    return __builtin_amdgcn_mfma_f32_16x16x32_bf16(a, b, c, 0, 0, 0);
}
static __device__ __forceinline__ f32x16 mfma32(bf16x8 a, bf16x8 b, f32x16 c) {
    return __builtin_amdgcn_mfma_f32_32x32x16_bf16(a, b, c, 0, 0, 0);
}

// sum of all 16 regs (15-add tree)
static __device__ __forceinline__ float tree_sum16(const f32x16& a) {
    float m[8];
#pragma unroll
    for (int r = 0; r < 8; ++r) m[r] = a[r] + a[r + 8];
#pragma unroll
    for (int off = 4; off; off >>= 1)
#pragma unroll
        for (int r = 0; r < off; ++r) m[r] += m[r + off];
    return m[0];
}

// P regs (8 f32, C-layout key groups) -> one B-operand bf16x8 (T12)
static __device__ __forceinline__ bf16x8 pack8(float s0, float s1, float s2,
        float s3, float s4, float s5, float s6, float s7) {
    unsigned c0 = cvt_pk_bf16(s0, s1);
    unsigned c1 = cvt_pk_bf16(s2, s3);
    unsigned c2 = cvt_pk_bf16(s4, s5);
    unsigned c3 = cvt_pk_bf16(s6, s7);
    asm volatile("v_permlane32_swap_b32 %0, %1" : "+v"(c0), "+v"(c2));
    asm volatile("v_permlane32_swap_b32 %0, %1" : "+v"(c1), "+v"(c3));
    u32x4 w; w[0] = c0; w[1] = c1; w[2] = c2; w[3] = c3;
    return __builtin_bit_cast(bf16x8, w);
}

// ---------------------- fp32 -> bf16 (v_cvt_pk packed) ---------------------
__global__ __launch_bounds__(256) void cvt_kernel(const float* __restrict__ src,
                                                  u16* __restrict__ dst, int n8) {
    int i = blockIdx.x * blockDim.x + threadIdx.x;
    int stride = gridDim.x * blockDim.x;
    for (; i < n8; i += stride) {
        float4v a = ((const float4v*)src)[2 * i];
        float4v b = ((const float4v*)src)[2 * i + 1];
        u32x4 o;
        o[0] = cvt_pk_bf16(a[0], a[1]); o[1] = cvt_pk_bf16(a[2], a[3]);
        o[2] = cvt_pk_bf16(b[0], b[1]); o[3] = cvt_pk_bf16(b[2], b[3]);
        ((u32x4*)dst)[i] = o;
    }
}

// four matrices in one launch; z==0 (Wq) pre-scaled by CEXP
__global__ __launch_bounds__(256) void cvt4_kernel(const float* __restrict__ s0,
        const float* __restrict__ s1, const float* __restrict__ s2,
        const float* __restrict__ s3, u16* __restrict__ d0, u16* __restrict__ d1,
        u16* __restrict__ d2, u16* __restrict__ d3, int n8) {
    const int z = blockIdx.y;
    const float* src = (z == 0) ? s0 : (z == 1) ? s1 : (z == 2) ? s2 : s3;
    u16* dst = (z == 0) ? d0 : (z == 1) ? d1 : (z == 2) ? d2 : d3;
    const float sc = (z == 0) ? CEXP : 1.0f;
    int i = blockIdx.x * blockDim.x + threadIdx.x;
    int stride = gridDim.x * blockDim.x;
    for (; i < n8; i += stride) {
        float4v a = ((const float4v*)src)[2 * i];
        float4v b = ((const float4v*)src)[2 * i + 1];
        u32x4 o;
        o[0] = cvt_pk_bf16(a[0] * sc, a[1] * sc);
        o[1] = cvt_pk_bf16(a[2] * sc, a[3] * sc);
        o[2] = cvt_pk_bf16(b[0] * sc, b[1] * sc);
        o[3] = cvt_pk_bf16(b[2] * sc, b[3] * sc);
        ((u32x4*)dst)[i] = o;
    }
}

// ----------------- GEMM, dbuf + single barrier per K-step ------------------
// 128x128 tile, BK=32, K=1024, 256 thr (4 waves 2x2). Stage(next) issued
// BEFORE compute(cur); one __syncthreads per K-step.
// MODE 0 (fused, grid 768): id<512 -> z=id>>8 Q/K proj (col-bias, bf16 out,
//   Wq path pre-scaled); id>=512 -> V^T gemm: C = Wv . x_b^T (row-bias bv),
//   out row-major [1024 hd][2048 t] at vt + b*1024*2048 (coalesced in t).
// MODE 1 (grid 256): out-proj, f32 out + col-bias.
template<int MODE>
__global__ __launch_bounds__(256) void gemm2(const u16* __restrict__ xb,
        const u16* __restrict__ Wb, const float* __restrict__ bq,
        const float* __restrict__ bk, const float* __restrict__ bvv,
        u16* __restrict__ outq, u16* __restrict__ vt, float* __restrict__ outf) {
    __shared__ alignas(16) u16 As[2][128 * 32];
    __shared__ alignas(16) u16 Bs[2][128 * 32];

    const int tid  = threadIdx.x;
    const int wave = tid >> 6, lane = tid & 63;
    const int lr = lane & 15, lg = lane >> 4;
    const int wr = wave >> 1, wc = wave & 1;
    const int K = 1024;

    const u16 *Ap, *Wp;
    int m0, n0, zb = 0;
    bool vtmode = false;
    const int id = blockIdx.x;
    if (MODE == 0) {
        if (id < 512) {
            zb = id >> 8; int r = id & 255;
            m0 = (r >> 3) * 128; n0 = (r & 7) * 128;
            Ap = xb; Wp = Wb + (size_t)zb * WNE;
        } else {
            int v = id - 512; zb = v >> 7; int r = v & 127;
            m0 = (r >> 4) * 128; n0 = (r & 15) * 128;
            Ap = Wb + 2 * WNE;                       // Wv
            Wp = xb + (size_t)zb * 2048 * 1024;      // x_b
            vtmode = true;
        }
    } else {
        m0 = (id >> 3) * 128; n0 = (id & 7) * 128;
        Ap = xb; Wp = Wb;
    }

    f32x4 acc[4][4];
#pragma unroll
    for (int m = 0; m < 4; ++m)
#pragma unroll
        for (int n = 0; n < 4; ++n) acc[m][n] = (f32x4){0.f, 0.f, 0.f, 0.f};

#define G_STAGE(BB_, KK_)                                                     \
    {                                                                         \
        _Pragma("unroll")                                                     \
        for (int it = 0; it < 2; ++it) {                                      \
            int c = it * 256 + tid;                                           \
            int row = c >> 2, cc = (c & 3) * 8;                               \
            load_lds16(Ap + (size_t)(m0 + row) * K + (KK_) + cc,              \
                       &As[BB_][(size_t)(it * 256 + wave * 64) * 8]);         \
            load_lds16(Wp + (size_t)(n0 + row) * K + (KK_) + cc,              \
                       &Bs[BB_][(size_t)(it * 256 + wave * 64) * 8]);         \
        }                                                                     \
    }

    G_STAGE(0, 0);
    __syncthreads();
    int cur = 0;
    for (int k0 = 0; k0 < K; k0 += 32) {
        if (k0 + 32 < K) G_STAGE(cur ^ 1, k0 + 32);

        bf16x8 af[4], bfm[4];
#pragma unroll
        for (int m = 0; m < 4; ++m)
            af[m] = *(const bf16x8*)&As[cur][(wr * 64 + m * 16 + lr) * 32 + lg * 8];
#pragma unroll
        for (int n = 0; n < 4; ++n)
            bfm[n] = *(const bf16x8*)&Bs[cur][(wc * 64 + n * 16 + lr) * 32 + lg * 8];
#pragma unroll
        for (int m = 0; m < 4; ++m)
#pragma unroll
            for (int n = 0; n < 4; ++n)
                acc[m][n] = mfma16(af[m], bfm[n], acc[m][n]);

        __syncthreads();   // drains vmcnt: next buffer published
        cur ^= 1;
    }
#undef G_STAGE

    if (MODE == 1) {
#pragma unroll
        for (int n = 0; n < 4; ++n) {
            int col = n0 + wc * 64 + n * 16 + lr;
            float bvl = bq[col];
#pragma unroll
            for (int m = 0; m < 4; ++m) {
                int row = m0 + wr * 64 + m * 16 + lg * 4;
#pragma unroll
                for (int r = 0; r < 4; ++r)
                    outf[(size_t)(row + r) * 1024 + col] = acc[m][n][r] + bvl;
            }
        }
    } else if (!vtmode) {
        const float* bias = zb ? bk : bq;
        const float bsc = zb ? 1.0f : CEXP;
#pragma unroll
        for (int n = 0; n < 4; ++n) {
            int col = n0 + wc * 64 + n * 16 + lr;
            float bvl = bias[col] * bsc;
#pragma unroll
            for (int m = 0; m < 4; ++m) {
                int row = m0 + wr * 64 + m * 16 + lg * 4;
#pragma unroll
                for (int r = 0; r < 4; ++r)
                    outq[(size_t)zb * XNE + (size_t)(row + r) * 1024 + col] =
                        f2bf(acc[m][n][r] + bvl);
            }
        }
    } else {
        // V^T: rows = hd (row-bias), cols = t (coalesced)
        u16* vo = vt + (size_t)zb * 1024 * 2048;
#pragma unroll
        for (int m = 0; m < 4; ++m) {
            int rowb = m0 + wr * 64 + m * 16 + lg * 4;
            float bvr[4];
#pragma unroll
            for (int r = 0; r < 4; ++r) bvr[r] = bvv[rowb + r];
#pragma unroll
            for (int n = 0; n < 4; ++n) {
                int col = n0 + wc * 64 + n * 16 + lr;
#pragma unroll
                for (int r = 0; r < 4; ++r)
                    vo[(size_t)(rowb + r) * 2048 + col] = f2bf(acc[m][n][r] + bvr[r]);
            }
        }
    }
}

// --------------------------- attention pass 1 ------------------------------
// KV-split flash partials, base-free exp2 softmax (Q pre-scaled by CEXP).
// 512-key chunks: slot s -> (qi, ch) with nch(qi) = (qi>>2)+1 (40 slots/bh).
// Grid 1280 XCD-mapped: i -> bh=(i&7)*4+(i>>3)/40, s=(i>>3)%40.
// Single-buffered K/V (16KB LDS); K and V^T staged via global_load_lds
// (V pre-transposed by the GEMM). NO setprio (m190: hurts barrier-synced
// lockstep waves; r12 confirmed -3..5us). nc==1 (qi<4): write Y directly.
__global__ __launch_bounds__(256) void attn_part(const u16* __restrict__ Qb,
        const u16* __restrict__ Kb, const u16* __restrict__ VTb,
        u16* __restrict__ Op, float* __restrict__ Ml, u16* __restrict__ Yb) {
    __shared__ alignas(16) u16 Ks[64 * 64];   // [key][d], XOR-swizzled 16B slots
    __shared__ alignas(16) u16 Vs[64 * 64];   // [d][key], XOR-swizzled 16B slots

    const int tid  = threadIdx.x;
    const int wave = tid >> 6, lane = tid & 63;
    const int lq = lane & 31, hi = lane >> 5;

    const int i0 = blockIdx.x;
    const int bh = (i0 & 7) * 4 + ((i0 >> 3) / 40);
    const int s  = (i0 >> 3) % 40;
    int qi = 0, ch = 0;
    {
        int cum = 0, found = 0;
#pragma unroll
        for (int j = 0; j < 16; ++j) {
            int n = (j >> 2) + 1;
            if (!found && s < cum + n) { qi = j; ch = s - cum; found = 1; }
            cum += n;
        }
    }
    const int nc = (qi >> 2) + 1;
    const int b = bh >> 4, h = bh & 15;
    const size_t rb = (size_t)b * TT;
    const int hoff = h * DH;
    const int q0w = qi * 128 + wave * 32;     // warp q base
    const int k0 = ch * 512;
    const int kend = qi * 128 + 128;
    const int k1 = (k0 + 512 < kend) ? k0 + 512 : kend;

    // staging coords: chunk c = it*256+tid -> row=c>>3, slot=c&7
    const int srow0 = tid >> 3, sl = tid & 7;
    const int srow1 = (256 + tid) >> 3;

    const u16* Kbh = Kb + rb * DD + hoff;
    const u16* Vbh = VTb + (size_t)bh * 64 * 2048;

    // Q fragments (B-operand): col=lane&31=q, k=(lane>>5)*8+j ; 4 chunks of 16
    bf16x8 qf[4];
    {
        const u16* qrow = Qb + (rb + q0w + lq) * DD + hoff + hi * 8;
#pragma unroll
        for (int kc = 0; kc < 4; ++kc) qf[kc] = *(const bf16x8*)(qrow + kc * 16);
    }

    f32x16 o0 = {}, o1 = {};
    float l_i = 0.f;

    for (int kv0 = k0; kv0 < k1; kv0 += 64) {
        __syncthreads();
        // K tile [64 key][64 d] and V^T tile [64 d][64 key], swizzled source
        load_lds16(Kbh + (size_t)(kv0 + srow0) * DD + (sl ^ (srow0 & 7)) * 8,
                   &Ks[(size_t)(wave * 64) * 8]);
        load_lds16(Kbh + (size_t)(kv0 + srow1) * DD + (sl ^ (srow1 & 7)) * 8,
                   &Ks[(size_t)(256 + wave * 64) * 8]);
        load_lds16(Vbh + (size_t)srow0 * 2048 + kv0 + (sl ^ (srow0 & 7)) * 8,
                   &Vs[(size_t)(wave * 64) * 8]);
        load_lds16(Vbh + (size_t)srow1 * 2048 + kv0 + (sl ^ (srow1 & 7)) * 8,
                   &Vs[(size_t)(256 + wave * 64) * 8]);
        __syncthreads();

        if (kv0 < q0w + 32) {
            const int rowm = lq & 7;
            const bool diag = (kv0 + 63 > q0w);
            const int qrel = q0w + lq - kv0;
            bf16x8 pb[4];

            // ---- keys 0..31
            {
                f32x16 st = {};
#pragma unroll
                for (int kc = 0; kc < 4; ++kc) {
                    bf16x8 kf = *(const bf16x8*)&Ks[lq * 64 + ((2 * kc + hi) ^ rowm) * 8];
                    st = mfma32(kf, qf[kc], st);
                }
                if (diag) {
#pragma unroll
                    for (int r = 0; r < 16; ++r) {
                        int key = (r & 3) + 8 * (r >> 2) + 4 * hi;
                        if (key > qrel) st[r] = -1e30f;
                    }
                }
#pragma unroll
                for (int r = 0; r < 16; ++r) st[r] = __builtin_amdgcn_exp2f(st[r]);
                l_i += tree_sum16(st);
                pb[0] = pack8(st[0], st[1], st[2], st[3], st[4], st[5], st[6], st[7]);
                pb[1] = pack8(st[8], st[9], st[10], st[11], st[12], st[13], st[14], st[15]);
            }
            // ---- keys 32..63
            {
                f32x16 st = {};
#pragma unroll
                for (int kc = 0; kc < 4; ++kc) {
                    bf16x8 kf = *(const bf16x8*)&Ks[(32 + lq) * 64 + ((2 * kc + hi) ^ rowm) * 8];
                    st = mfma32(kf, qf[kc], st);
                }
                if (diag) {
#pragma unroll
                    for (int r = 0; r < 16; ++r) {
                        int key = 32 + (r & 3) + 8 * (r >> 2) + 4 * hi;
                        if (key > qrel) st[r] = -1e30f;
                    }
                }
#pragma unroll
                for (int r = 0; r < 16; ++r) st[r] = __builtin_amdgcn_exp2f(st[r]);
                l_i += tree_sum16(st);
                pb[2] = pack8(st[0], st[1], st[2], st[3], st[4], st[5], st[6], st[7]);
                pb[3] = pack8(st[8], st[9], st[10], st[11], st[12], st[13], st[14], st[15]);
            }

            // O^T += V^T . P^T : A=V^T (row=d, swizzled read), B=P^T (col=q)
#pragma unroll
            for (int ks = 0; ks < 4; ++ks) {
                bf16x8 vf0 = *(const bf16x8*)&Vs[lq * 64        + ((ks * 2 + hi) ^ rowm) * 8];
                bf16x8 vf1 = *(const bf16x8*)&Vs[(32 + lq) * 64 + ((ks * 2 + hi) ^ rowm) * 8];
                o0 = mfma32(vf0, pb[ks], o0);
                o1 = mfma32(vf1, pb[ks], o1);
            }
        }
    }

    l_i += __shfl_xor(l_i, 32);
    const int col = wave * 32 + lq;

    if (nc == 1) {
        // single chunk: normalize and write Y directly
        const float inv = 1.0f / l_i;
        u16* yrow = Yb + (rb + q0w + lq) * DD + hoff;
#pragma unroll
        for (int g = 0; g < 4; ++g) {
            u16x4 p0, p1;
#pragma unroll
            for (int j = 0; j < 4; ++j) {
                p0[j] = f2bf(o0[4 * g + j] * inv);
                p1[j] = f2bf(o1[4 * g + j] * inv);
            }
            *(u16x4*)&yrow[8 * g + 4 * hi]      = p0;
            *(u16x4*)&yrow[32 + 8 * g + 4 * hi] = p1;
        }
    } else {
        const int slot = bh * 40 + s;
        u16* op = Op + (size_t)slot * 8192;
#pragma unroll
        for (int r = 0; r < 16; ++r) {
            const int d0 = (r & 3) + 8 * (r >> 2) + 4 * hi;
            op[d0 * 128 + col]        = f2bf(o0[r]);
            op[(32 + d0) * 128 + col] = f2bf(o1[r]);
        }
        if (hi == 0) Ml[(size_t)slot * 128 + col] = l_i;
    }
}

// --------------------------- attention pass 2 ------------------------------
// grid 512 = 32 bh x 16 qi; 256 thr. qi<4 handled by pass1 (early return).
// O = sum_c O_c / sum_c l_c (common exp2 base, no max bookkeeping).
__global__ __launch_bounds__(256) void attn_merge(const u16* __restrict__ Op,
        const float* __restrict__ Ml, u16* __restrict__ Yb) {
    const int bq = blockIdx.x;
    const int bh = bq >> 4, qi = bq & 15;
    const int nc = (qi >> 2) + 1;
    if (nc == 1) return;
    int cum = 0;
#pragma unroll
    for (int j = 0; j < 16; ++j) cum += (j < qi) ? ((j >> 2) + 1) : 0;
    const int s0 = bh * 40 + cum;

    const int t = threadIdx.x;
    const int row = t >> 1, dh = (t & 1) * 32;

    float L = 0.f;
    float acc[32];
#pragma unroll
    for (int d = 0; d < 32; ++d) acc[d] = 0.f;
#pragma unroll
    for (int c = 0; c < 4; ++c) {
        if (c < nc) {
            L += Ml[(size_t)(s0 + c) * 128 + row];
            const u16* op = Op + (size_t)(s0 + c) * 8192 + row;
#pragma unroll
            for (int d = 0; d < 32; ++d)
                acc[d] += bf2f(op[(dh + d) * 128]);
        }
    }
    const float inv = 1.0f / L;

    const int b = bh >> 4, h = bh & 15;
    u16* yrow = Yb + ((size_t)(b * TT + qi * 128 + row)) * DD + h * DH + dh;
#pragma unroll
    for (int g = 0; g < 8; ++g) {
        u16x4 p;
#pragma unroll
        for (int j = 0; j < 4; ++j) p[j] = f2bf(acc[4 * g + j] * inv);
        *(u16x4*)&yrow[4 * g] = p;
    }
}

// ------------------------------- launcher ----------------------------------
extern "C" void kernel_launch(void* const* d_in, const int* in_sizes, int n_in,
                              void* d_out, int out_size, void* d_ws, size_t ws_size,
                              hipStream_t stream) {
    const float* x  = (const float*)d_in[0];
    const float* Wq = (const float*)d_in[1];
    const float* bq = (const float*)d_in[2];
    const float* Wk = (const float*)d_in[3];
    const float* bk = (const float*)d_in[4];
    const float* Wv = (const float*)d_in[5];
    const float* bv = (const float*)d_in[6];
    const float* Wo = (const float*)d_in[7];
    const float* bo = (const float*)d_in[8];
    float* out = (float*)d_out;

    u16* xb  = (u16*)d_ws;
    u16* Wb  = xb  + XNE;         // Wq,Wk,Wv stacked: 3*WNE
    u16* Wob = Wb  + 3 * WNE;
    u16* QKV = Wob + WNE;         // Q, K, VT stacked: 3*XNE
    u16* Yb  = QKV + 3 * XNE;
    u16* Op  = Yb  + XNE;                             // bf16 [1280][64][128]
    float* Ml = (float*)(Op + (size_t)NSLOT * 8192);  // f32 [1280][128]

    cvt_kernel<<<1024, 256, 0, stream>>>(x, xb, (int)(XNE / 8));
    cvt4_kernel<<<dim3(128, 4), 256, 0, stream>>>(Wq, Wk, Wv, Wo,
            Wb, Wb + WNE, Wb + 2 * WNE, Wob, (int)(WNE / 8));

    // fused Q-proj, K-proj, V^T gemm (768 blocks)
    gemm2<0><<<768, 256, 0, stream>>>(xb, Wb, bq, bk, bv,
                                      QKV, QKV + 2 * XNE, nullptr);
    attn_part<<<NSLOT, 256, 0, stream>>>(QKV, QKV + XNE, QKV + 2 * XNE,
                                         Op, Ml, Yb);
    attn_merge<<<512, 256, 0, stream>>>(Op, Ml, Yb);
    // out-proj (f32 out + bias)
    gemm2<1><<<256, 256, 0, stream>>>(Yb, Wob, bo, nullptr, nullptr,
                                      nullptr, nullptr, out);
}

// Round 14
// 114.784 us; speedup vs baseline: 1.1156x; 1.0134x over previous
//
#include <hip/hip_runtime.h>
#include <stdint.h>

// ---------------------------------------------------------------------------
// CausalSelfAttention (B=2, T=2048, D=1024, H=16, Dh=64), fp32 in/out.
// cvt5 (one launch, Wq pre-scaled) -> fused {Q,K proj + V^T} gemm (dbuf,
// 1 barrier/K-step) -> flash attn KV-split (512-key chunks, 128-key LDS
// stage) -> merge -> out gemm.
// ---------------------------------------------------------------------------

typedef unsigned short u16;
typedef __attribute__((ext_vector_type(8)))  __bf16 bf16x8;   // 4 VGPR MFMA A/B frag
typedef __attribute__((ext_vector_type(4)))  float  f32x4;    // 16x16 C/D frag
typedef __attribute__((ext_vector_type(16))) float  f32x16;   // 32x32 C/D frag
typedef __attribute__((ext_vector_type(4)))  float  float4v;
typedef __attribute__((ext_vector_type(4)))  unsigned short u16x4;
typedef __attribute__((ext_vector_type(4)))  unsigned int   u32x4;
typedef __attribute__((ext_vector_type(8)))  short  short8;   // raw 16B load

#define BB 2
#define TT 2048
#define DD 1024
#define HH 16
#define DH 64
#define MM (BB*TT)          // 4096 rows
#define NSLOT 1280          // 32 bh * 40 (qi,chunk) slots (512-key chunks)
#define CEXP 0.18033688011f // 0.125 * log2(e), folded into Wq/bq
#define XNE ((size_t)MM*DD)
#define WNE ((size_t)DD*DD)

static __device__ __forceinline__ u16 f2bf(float f) {
    uint32_t u = __builtin_bit_cast(uint32_t, f);
    u += 0x7FFFu + ((u >> 16) & 1u);          // round-to-nearest-even
    return (u16)(u >> 16);
}
static __device__ __forceinline__ float bf2f(u16 v) {
    uint32_t u = (uint32_t)v << 16;
    return __builtin_bit_cast(float, u);
}

static __device__ __forceinline__ unsigned cvt_pk_bf16(float a, float b) {
    unsigned r;
    asm("v_cvt_pk_bf16_f32 %0, %1, %2" : "=v"(r) : "v"(a), "v"(b));
    return r;
}

// global(16B per lane) -> LDS direct copy (wave-uniform dst base + lane*16).
static __device__ __forceinline__ void load_lds16(const u16* g, const u16* lds_base) {
    __builtin_amdgcn_global_load_lds(
        (const __attribute__((address_space(1))) void*)(uintptr_t)g,
        (__attribute__((address_space(3)))  void*)(uint32_t)(uintptr_t)lds_base,
        16u, 0, 0u);
}

static __device__ __forceinline__ f32x4 mfma16(bf16x8 a, bf16x8 b, f32x4 c) {
    return __builtin_amdgcn_mfma_f32_16x16x32_bf16(a, b, c, 0, 0, 0);
}
static __device__ __forceinline__ f32x16 mfma32(bf16x8 a, bf16x8 b, f32x16 c) {
    return __builtin_amdgcn_mfma_f32_32x32x16_bf16(a, b, c, 0, 0, 0);
}

// sum of all 16 regs (15-add tree)
static __device__ __forceinline__ float tree_sum16(const f32x16& a) {
    float m[8];
#pragma unroll
    for (int r = 0; r < 8; ++r) m[r] = a[r] + a[r + 8];
#pragma unroll
    for (int off = 4; off; off >>= 1)
#pragma unroll
        for (int r = 0; r < off; ++r) m[r] += m[r + off];
    return m[0];
}

// P regs (8 f32, C-layout key groups) -> one B-operand bf16x8 (T12)
static __device__ __forceinline__ bf16x8 pack8(float s0, float s1, float s2,
        float s3, float s4, float s5, float s6, float s7) {
    unsigned c0 = cvt_pk_bf16(s0, s1);
    unsigned c1 = cvt_pk_bf16(s2, s3);
    unsigned c2 = cvt_pk_bf16(s4, s5);
    unsigned c3 = cvt_pk_bf16(s6, s7);
    asm volatile("v_permlane32_swap_b32 %0, %1" : "+v"(c0), "+v"(c2));
    asm volatile("v_permlane32_swap_b32 %0, %1" : "+v"(c1), "+v"(c3));
    u32x4 w; w[0] = c0; w[1] = c1; w[2] = c2; w[3] = c3;
    return __builtin_bit_cast(bf16x8, w);
}

// ------------- fp32 -> bf16, ALL tensors in one launch (cvt_pk) ------------
// grid (128, 8): y<4 -> quarter y of x; y>=4 -> weight y-4 (Wq scaled).
__global__ __launch_bounds__(256) void cvt5_kernel(const float* __restrict__ x,
        const float* __restrict__ w0, const float* __restrict__ w1,
        const float* __restrict__ w2, const float* __restrict__ w3,
        u16* __restrict__ xd, u16* __restrict__ d0, u16* __restrict__ d1,
        u16* __restrict__ d2, u16* __restrict__ d3) {
    const int y = blockIdx.y;
    const float* src;
    u16* dst;
    float sc = 1.0f;
    if (y < 4) { src = x + (size_t)y * (XNE / 4); dst = xd + (size_t)y * (XNE / 4); }
    else if (y == 4) { src = w0; dst = d0; sc = CEXP; }
    else if (y == 5) { src = w1; dst = d1; }
    else if (y == 6) { src = w2; dst = d2; }
    else            { src = w3; dst = d3; }
    const int n8 = (int)(WNE / 8);            // all segments are 1M f32
    int i = blockIdx.x * blockDim.x + threadIdx.x;
    int stride = gridDim.x * blockDim.x;
    for (; i < n8; i += stride) {
        float4v a = ((const float4v*)src)[2 * i];
        float4v b = ((const float4v*)src)[2 * i + 1];
        u32x4 o;
        o[0] = cvt_pk_bf16(a[0] * sc, a[1] * sc);
        o[1] = cvt_pk_bf16(a[2] * sc, a[3] * sc);
        o[2] = cvt_pk_bf16(b[0] * sc, b[1] * sc);
        o[3] = cvt_pk_bf16(b[2] * sc, b[3] * sc);
        ((u32x4*)dst)[i] = o;
    }
}

// ----------------- GEMM, dbuf + single barrier per K-step ------------------
// 128x128 tile, BK=32, K=1024, 256 thr (4 waves 2x2). Stage(next) issued
// BEFORE compute(cur); one __syncthreads per K-step.
// MODE 0 (fused, grid 768): id<512 -> z=id>>8 Q/K proj (col-bias, bf16 out,
//   Wq path pre-scaled); id>=512 -> V^T gemm: C = Wv . x_b^T (row-bias bv),
//   out row-major [1024 hd][2048 t] at vt + b*1024*2048 (coalesced in t).
// MODE 1 (grid 256): out-proj, f32 out + col-bias.
template<int MODE>
__global__ __launch_bounds__(256) void gemm2(const u16* __restrict__ xb,
        const u16* __restrict__ Wb, const float* __restrict__ bq,
        const float* __restrict__ bk, const float* __restrict__ bvv,
        u16* __restrict__ outq, u16* __restrict__ vt, float* __restrict__ outf) {
    __shared__ alignas(16) u16 As[2][128 * 32];
    __shared__ alignas(16) u16 Bs[2][128 * 32];

    const int tid  = threadIdx.x;
    const int wave = tid >> 6, lane = tid & 63;
    const int lr = lane & 15, lg = lane >> 4;
    const int wr = wave >> 1, wc = wave & 1;
    const int K = 1024;

    const u16 *Ap, *Wp;
    int m0, n0, zb = 0;
    bool vtmode = false;
    const int id = blockIdx.x;
    if (MODE == 0) {
        if (id < 512) {
            zb = id >> 8; int r = id & 255;
            m0 = (r >> 3) * 128; n0 = (r & 7) * 128;
            Ap = xb; Wp = Wb + (size_t)zb * WNE;
        } else {
            int v = id - 512; zb = v >> 7; int r = v & 127;
            m0 = (r >> 4) * 128; n0 = (r & 15) * 128;
            Ap = Wb + 2 * WNE;                       // Wv
            Wp = xb + (size_t)zb * 2048 * 1024;      // x_b
            vtmode = true;
        }
    } else {
        m0 = (id >> 3) * 128; n0 = (id & 7) * 128;
        Ap = xb; Wp = Wb;
    }

    f32x4 acc[4][4];
#pragma unroll
    for (int m = 0; m < 4; ++m)
#pragma unroll
        for (int n = 0; n < 4; ++n) acc[m][n] = (f32x4){0.f, 0.f, 0.f, 0.f};

#define G_STAGE(BB_, KK_)                                                     \
    {                                                                         \
        _Pragma("unroll")                                                     \
        for (int it = 0; it < 2; ++it) {                                      \
            int c = it * 256 + tid;                                           \
            int row = c >> 2, cc = (c & 3) * 8;                               \
            load_lds16(Ap + (size_t)(m0 + row) * K + (KK_) + cc,              \
                       &As[BB_][(size_t)(it * 256 + wave * 64) * 8]);         \
            load_lds16(Wp + (size_t)(n0 + row) * K + (KK_) + cc,              \
                       &Bs[BB_][(size_t)(it * 256 + wave * 64) * 8]);         \
        }                                                                     \
    }

    G_STAGE(0, 0);
    __syncthreads();
    int cur = 0;
    for (int k0 = 0; k0 < K; k0 += 32) {
        if (k0 + 32 < K) G_STAGE(cur ^ 1, k0 + 32);

        bf16x8 af[4], bfm[4];
#pragma unroll
        for (int m = 0; m < 4; ++m)
            af[m] = *(const bf16x8*)&As[cur][(wr * 64 + m * 16 + lr) * 32 + lg * 8];
#pragma unroll
        for (int n = 0; n < 4; ++n)
            bfm[n] = *(const bf16x8*)&Bs[cur][(wc * 64 + n * 16 + lr) * 32 + lg * 8];
#pragma unroll
        for (int m = 0; m < 4; ++m)
#pragma unroll
            for (int n = 0; n < 4; ++n)
                acc[m][n] = mfma16(af[m], bfm[n], acc[m][n]);

        __syncthreads();   // drains vmcnt: next buffer published
        cur ^= 1;
    }
#undef G_STAGE

    if (MODE == 1) {
#pragma unroll
        for (int n = 0; n < 4; ++n) {
            int col = n0 + wc * 64 + n * 16 + lr;
            float bvl = bq[col];
#pragma unroll
            for (int m = 0; m < 4; ++m) {
                int row = m0 + wr * 64 + m * 16 + lg * 4;
#pragma unroll
                for (int r = 0; r < 4; ++r)
                    outf[(size_t)(row + r) * 1024 + col] = acc[m][n][r] + bvl;
            }
        }
    } else if (!vtmode) {
        const float* bias = zb ? bk : bq;
        const float bsc = zb ? 1.0f : CEXP;
#pragma unroll
        for (int n = 0; n < 4; ++n) {
            int col = n0 + wc * 64 + n * 16 + lr;
            float bvl = bias[col] * bsc;
#pragma unroll
            for (int m = 0; m < 4; ++m) {
                int row = m0 + wr * 64 + m * 16 + lg * 4;
#pragma unroll
                for (int r = 0; r < 4; ++r)
                    outq[(size_t)zb * XNE + (size_t)(row + r) * 1024 + col] =
                        f2bf(acc[m][n][r] + bvl);
            }
        }
    } else {
        // V^T: rows = hd (row-bias), cols = t (coalesced)
        u16* vo = vt + (size_t)zb * 1024 * 2048;
#pragma unroll
        for (int m = 0; m < 4; ++m) {
            int rowb = m0 + wr * 64 + m * 16 + lg * 4;
            float bvr[4];
#pragma unroll
            for (int r = 0; r < 4; ++r) bvr[r] = bvv[rowb + r];
#pragma unroll
            for (int n = 0; n < 4; ++n) {
                int col = n0 + wc * 64 + n * 16 + lr;
#pragma unroll
                for (int r = 0; r < 4; ++r)
                    vo[(size_t)(rowb + r) * 2048 + col] = f2bf(acc[m][n][r] + bvr[r]);
            }
        }
    }
}

// --------------------------- attention pass 1 ------------------------------
// KV-split flash partials, base-free exp2 softmax (Q pre-scaled by CEXP).
// 512-key chunks: slot s -> (qi, ch) with nch(qi) = (qi>>2)+1 (40 slots/bh).
// Grid 1280 XCD-mapped: i -> bh=(i&7)*4+(i>>3)/40, s=(i>>3)%40.
// 128-KEY LDS STAGE (32KB): one barrier pair covers TWO 64-key compute
// sub-tiles -> half the barrier drains, ILP across independent sub-tiles.
// K and V^T staged via global_load_lds (V pre-transposed by the GEMM).
// No setprio (m190/r12: hurts lockstep waves). nc==1 (qi<4): write Y direct.
__global__ __launch_bounds__(256) void attn_part(const u16* __restrict__ Qb,
        const u16* __restrict__ Kb, const u16* __restrict__ VTb,
        u16* __restrict__ Op, float* __restrict__ Ml, u16* __restrict__ Yb) {
    __shared__ alignas(16) u16 Ks[128 * 64];  // [key][d], XOR-swizzled 16B slots
    __shared__ alignas(16) u16 Vs[64 * 128];  // [d][key], XOR-swizzled 16B slots

    const int tid  = threadIdx.x;
    const int wave = tid >> 6, lane = tid & 63;
    const int lq = lane & 31, hi = lane >> 5;

    const int i0 = blockIdx.x;
    const int bh = (i0 & 7) * 4 + ((i0 >> 3) / 40);
    const int s  = (i0 >> 3) % 40;
    int qi = 0, ch = 0;
    {
        int cum = 0, found = 0;
#pragma unroll
        for (int j = 0; j < 16; ++j) {
            int n = (j >> 2) + 1;
            if (!found && s < cum + n) { qi = j; ch = s - cum; found = 1; }
            cum += n;
        }
    }
    const int nc = (qi >> 2) + 1;
    const int b = bh >> 4, h = bh & 15;
    const size_t rb = (size_t)b * TT;
    const int hoff = h * DH;
    const int q0w = qi * 128 + wave * 32;     // warp q base
    const int k0 = ch * 512;
    const int kend = qi * 128 + 128;          // multiple of 128
    const int k1 = (k0 + 512 < kend) ? k0 + 512 : kend;

    const u16* Kbh = Kb + rb * DD + hoff;
    const u16* Vbh = VTb + (size_t)bh * 64 * 2048;

    // Q fragments (B-operand): col=lane&31=q, k=(lane>>5)*8+j ; 4 chunks of 16
    bf16x8 qf[4];
    {
        const u16* qrow = Qb + (rb + q0w + lq) * DD + hoff + hi * 8;
#pragma unroll
        for (int kc = 0; kc < 4; ++kc) qf[kc] = *(const bf16x8*)(qrow + kc * 16);
    }

    f32x16 o0 = {}, o1 = {};
    float l_i = 0.f;
    const int rowm = lq & 7;

    for (int kv0 = k0; kv0 < k1; kv0 += 128) {
        __syncthreads();
        // stage K [128 key][64 d] (8 slots/row) and V^T [64 d][128 key]
        // (16 slots/row); source pre-swizzled, LDS linear (rule 21)
#pragma unroll
        for (int it = 0; it < 4; ++it) {
            int c = it * 256 + tid;
            int krow = c >> 3, ksl = c & 7;
            load_lds16(Kbh + (size_t)(kv0 + krow) * DD + ((ksl ^ (krow & 7)) * 8),
                       &Ks[(size_t)(it * 256 + wave * 64) * 8]);
        }
#pragma unroll
        for (int it = 0; it < 4; ++it) {
            int c = it * 256 + tid;
            int vrow = c >> 4, vsl = c & 15;
            load_lds16(Vbh + (size_t)vrow * 2048 + kv0 + ((vsl ^ (vrow & 7)) * 8),
                       &Vs[(size_t)(it * 256 + wave * 64) * 8]);
        }
        __syncthreads();

#pragma unroll
        for (int sub = 0; sub < 2; ++sub) {
            const int kb = kv0 + sub * 64;
            if (kb < q0w + 32) {
                const bool diag = (kb + 63 > q0w);
                const int qrel = q0w + lq - kb;
                bf16x8 pb[4];

                // ---- keys kb+0..31
                {
                    f32x16 st = {};
#pragma unroll
                    for (int kc = 0; kc < 4; ++kc) {
                        bf16x8 kf = *(const bf16x8*)&Ks[(sub * 64 + lq) * 64 +
                                                        ((2 * kc + hi) ^ rowm) * 8];
                        st = mfma32(kf, qf[kc], st);
                    }
                    if (diag) {
#pragma unroll
                        for (int r = 0; r < 16; ++r) {
                            int key = (r & 3) + 8 * (r >> 2) + 4 * hi;
                            if (key > qrel) st[r] = -1e30f;
                        }
                    }
#pragma unroll
                    for (int r = 0; r < 16; ++r) st[r] = __builtin_amdgcn_exp2f(st[r]);
                    l_i += tree_sum16(st);
                    pb[0] = pack8(st[0], st[1], st[2], st[3], st[4], st[5], st[6], st[7]);
                    pb[1] = pack8(st[8], st[9], st[10], st[11], st[12], st[13], st[14], st[15]);
                }
                // ---- keys kb+32..63
                {
                    f32x16 st = {};
#pragma unroll
                    for (int kc = 0; kc < 4; ++kc) {
                        bf16x8 kf = *(const bf16x8*)&Ks[(sub * 64 + 32 + lq) * 64 +
                                                        ((2 * kc + hi) ^ rowm) * 8];
                        st = mfma32(kf, qf[kc], st);
                    }
                    if (diag) {
#pragma unroll
                        for (int r = 0; r < 16; ++r) {
                            int key = 32 + (r & 3) + 8 * (r >> 2) + 4 * hi;
                            if (key > qrel) st[r] = -1e30f;
                        }
                    }
#pragma unroll
                    for (int r = 0; r < 16; ++r) st[r] = __builtin_amdgcn_exp2f(st[r]);
                    l_i += tree_sum16(st);
                    pb[2] = pack8(st[0], st[1], st[2], st[3], st[4], st[5], st[6], st[7]);
                    pb[3] = pack8(st[8], st[9], st[10], st[11], st[12], st[13], st[14], st[15]);
                }

                // O^T += V^T . P^T : A=V^T (row=d, swizzled read), B=P^T
#pragma unroll
                for (int ks = 0; ks < 4; ++ks) {
                    bf16x8 vf0 = *(const bf16x8*)&Vs[lq * 128 +
                                    (sub * 8 + ((ks * 2 + hi) ^ rowm)) * 8];
                    bf16x8 vf1 = *(const bf16x8*)&Vs[(32 + lq) * 128 +
                                    (sub * 8 + ((ks * 2 + hi) ^ rowm)) * 8];
                    o0 = mfma32(vf0, pb[ks], o0);
                    o1 = mfma32(vf1, pb[ks], o1);
                }
            }
        }
    }

    l_i += __shfl_xor(l_i, 32);
    const int col = wave * 32 + lq;

    if (nc == 1) {
        // single chunk: normalize and write Y directly
        const float inv = 1.0f / l_i;
        u16* yrow = Yb + (rb + q0w + lq) * DD + hoff;
#pragma unroll
        for (int g = 0; g < 4; ++g) {
            u16x4 p0, p1;
#pragma unroll
            for (int j = 0; j < 4; ++j) {
                p0[j] = f2bf(o0[4 * g + j] * inv);
                p1[j] = f2bf(o1[4 * g + j] * inv);
            }
            *(u16x4*)&yrow[8 * g + 4 * hi]      = p0;
            *(u16x4*)&yrow[32 + 8 * g + 4 * hi] = p1;
        }
    } else {
        const int slot = bh * 40 + s;
        u16* op = Op + (size_t)slot * 8192;
#pragma unroll
        for (int r = 0; r < 16; ++r) {
            const int d0 = (r & 3) + 8 * (r >> 2) + 4 * hi;
            op[d0 * 128 + col]        = f2bf(o0[r]);
            op[(32 + d0) * 128 + col] = f2bf(o1[r]);
        }
        if (hi == 0) Ml[(size_t)slot * 128 + col] = l_i;
    }
}

// --------------------------- attention pass 2 ------------------------------
// grid 512 = 32 bh x 16 qi; 256 thr. qi<4 handled by pass1 (early return).
// O = sum_c O_c / sum_c l_c (common exp2 base, no max bookkeeping).
__global__ __launch_bounds__(256) void attn_merge(const u16* __restrict__ Op,
        const float* __restrict__ Ml, u16* __restrict__ Yb) {
    const int bq = blockIdx.x;
    const int bh = bq >> 4, qi = bq & 15;
    const int nc = (qi >> 2) + 1;
    if (nc == 1) return;
    int cum = 0;
#pragma unroll
    for (int j = 0; j < 16; ++j) cum += (j < qi) ? ((j >> 2) + 1) : 0;
    const int s0 = bh * 40 + cum;

    const int t = threadIdx.x;
    const int row = t >> 1, dh = (t & 1) * 32;

    float L = 0.f;
    float acc[32];
#pragma unroll
    for (int d = 0; d < 32; ++d) acc[d] = 0.f;
#pragma unroll
    for (int c = 0; c < 4; ++c) {
        if (c < nc) {
            L += Ml[(size_t)(s0 + c) * 128 + row];
            const u16* op = Op + (size_t)(s0 + c) * 8192 + row;
#pragma unroll
            for (int d = 0; d < 32; ++d)
                acc[d] += bf2f(op[(dh + d) * 128]);
        }
    }
    const float inv = 1.0f / L;

    const int b = bh >> 4, h = bh & 15;
    u16* yrow = Yb + ((size_t)(b * TT + qi * 128 + row)) * DD + h * DH + dh;
#pragma unroll
    for (int g = 0; g < 8; ++g) {
        u16x4 p;
#pragma unroll
        for (int j = 0; j < 4; ++j) p[j] = f2bf(acc[4 * g + j] * inv);
        *(u16x4*)&yrow[4 * g] = p;
    }
}

// ------------------------------- launcher ----------------------------------
extern "C" void kernel_launch(void* const* d_in, const int* in_sizes, int n_in,
                              void* d_out, int out_size, void* d_ws, size_t ws_size,
                              hipStream_t stream) {
    const float* x  = (const float*)d_in[0];
    const float* Wq = (const float*)d_in[1];
    const float* bq = (const float*)d_in[2];
    const float* Wk = (const float*)d_in[3];
    const float* bk = (const float*)d_in[4];
    const float* Wv = (const float*)d_in[5];
    const float* bv = (const float*)d_in[6];
    const float* Wo = (const float*)d_in[7];
    const float* bo = (const float*)d_in[8];
    float* out = (float*)d_out;

    u16* xb  = (u16*)d_ws;
    u16* Wb  = xb  + XNE;         // Wq,Wk,Wv stacked: 3*WNE
    u16* Wob = Wb  + 3 * WNE;
    u16* QKV = Wob + WNE;         // Q, K, VT stacked: 3*XNE
    u16* Yb  = QKV + 3 * XNE;
    u16* Op  = Yb  + XNE;                             // bf16 [1280][64][128]
    float* Ml = (float*)(Op + (size_t)NSLOT * 8192);  // f32 [1280][128]

    // all fp32->bf16 conversions in one launch
    cvt5_kernel<<<dim3(128, 8), 256, 0, stream>>>(x, Wq, Wk, Wv, Wo,
            xb, Wb, Wb + WNE, Wb + 2 * WNE, Wob);

    // fused Q-proj, K-proj, V^T gemm (768 blocks)
    gemm2<0><<<768, 256, 0, stream>>>(xb, Wb, bq, bk, bv,
                                      QKV, QKV + 2 * XNE, nullptr);
    attn_part<<<NSLOT, 256, 0, stream>>>(QKV, QKV + XNE, QKV + 2 * XNE,
                                         Op, Ml, Yb);
    attn_merge<<<512, 256, 0, stream>>>(Op, Ml, Yb);
    // out-proj (f32 out + bias)
    gemm2<1><<<256, 256, 0, stream>>>(Yb, Wob, bo, nullptr, nullptr,
                                      nullptr, nullptr, out);
}

// Round 15
// 114.229 us; speedup vs baseline: 1.1210x; 1.0049x over previous
//
#include <hip/hip_runtime.h>
#include <stdint.h>

// ---------------------------------------------------------------------------
// CausalSelfAttention (B=2, T=2048, D=1024, H=16, Dh=64), fp32 in/out.
// cvt5 (one launch, Wq pre-scaled) -> fused {Q,K proj + V^T} gemm (dbuf,
// 1 barrier/K-step) -> flash attn KV-split (512-key chunks, 128-key LDS
// stage, l via ones-MFMA, longest-first) -> merge -> out gemm.
// ---------------------------------------------------------------------------

typedef unsigned short u16;
typedef __attribute__((ext_vector_type(8)))  __bf16 bf16x8;   // 4 VGPR MFMA A/B frag
typedef __attribute__((ext_vector_type(4)))  float  f32x4;    // 16x16 C/D frag
typedef __attribute__((ext_vector_type(16))) float  f32x16;   // 32x32 C/D frag
typedef __attribute__((ext_vector_type(4)))  float  float4v;
typedef __attribute__((ext_vector_type(4)))  unsigned short u16x4;
typedef __attribute__((ext_vector_type(4)))  unsigned int   u32x4;
typedef __attribute__((ext_vector_type(8)))  short  short8;   // raw 16B load

#define BB 2
#define TT 2048
#define DD 1024
#define HH 16
#define DH 64
#define MM (BB*TT)          // 4096 rows
#define NSLOT 1280          // 32 bh * 40 (qi,chunk) slots (512-key chunks)
#define CEXP 0.18033688011f // 0.125 * log2(e), folded into Wq/bq
#define XNE ((size_t)MM*DD)
#define WNE ((size_t)DD*DD)

static __device__ __forceinline__ u16 f2bf(float f) {
    uint32_t u = __builtin_bit_cast(uint32_t, f);
    u += 0x7FFFu + ((u >> 16) & 1u);          // round-to-nearest-even
    return (u16)(u >> 16);
}
static __device__ __forceinline__ float bf2f(u16 v) {
    uint32_t u = (uint32_t)v << 16;
    return __builtin_bit_cast(float, u);
}

static __device__ __forceinline__ unsigned cvt_pk_bf16(float a, float b) {
    unsigned r;
    asm("v_cvt_pk_bf16_f32 %0, %1, %2" : "=v"(r) : "v"(a), "v"(b));
    return r;
}

// global(16B per lane) -> LDS direct copy (wave-uniform dst base + lane*16).
static __device__ __forceinline__ void load_lds16(const u16* g, const u16* lds_base) {
    __builtin_amdgcn_global_load_lds(
        (const __attribute__((address_space(1))) void*)(uintptr_t)g,
        (__attribute__((address_space(3)))  void*)(uint32_t)(uintptr_t)lds_base,
        16u, 0, 0u);
}

static __device__ __forceinline__ f32x4 mfma16(bf16x8 a, bf16x8 b, f32x4 c) {
    return __builtin_amdgcn_mfma_f32_16x16x32_bf16(a, b, c, 0, 0, 0);
}
static __device__ __forceinline__ f32x16 mfma32(bf16x8 a, bf16x8 b, f32x16 c) {
    return __builtin_amdgcn_mfma_f32_32x32x16_bf16(a, b, c, 0, 0, 0);
}

// P regs (8 f32, C-layout key groups) -> one B-operand bf16x8 (T12)
static __device__ __forceinline__ bf16x8 pack8(float s0, float s1, float s2,
        float s3, float s4, float s5, float s6, float s7) {
    unsigned c0 = cvt_pk_bf16(s0, s1);
    unsigned c1 = cvt_pk_bf16(s2, s3);
    unsigned c2 = cvt_pk_bf16(s4, s5);
    unsigned c3 = cvt_pk_bf16(s6, s7);
    asm volatile("v_permlane32_swap_b32 %0, %1" : "+v"(c0), "+v"(c2));
    asm volatile("v_permlane32_swap_b32 %0, %1" : "+v"(c1), "+v"(c3));
    u32x4 w; w[0] = c0; w[1] = c1; w[2] = c2; w[3] = c3;
    return __builtin_bit_cast(bf16x8, w);
}

// ------------- fp32 -> bf16, ALL tensors in one launch (cvt_pk) ------------
// grid (128, 8): y<4 -> quarter y of x; y>=4 -> weight y-4 (Wq scaled).
__global__ __launch_bounds__(256) void cvt5_kernel(const float* __restrict__ x,
        const float* __restrict__ w0, const float* __restrict__ w1,
        const float* __restrict__ w2, const float* __restrict__ w3,
        u16* __restrict__ xd, u16* __restrict__ d0, u16* __restrict__ d1,
        u16* __restrict__ d2, u16* __restrict__ d3) {
    const int y = blockIdx.y;
    const float* src;
    u16* dst;
    float sc = 1.0f;
    if (y < 4) { src = x + (size_t)y * (XNE / 4); dst = xd + (size_t)y * (XNE / 4); }
    else if (y == 4) { src = w0; dst = d0; sc = CEXP; }
    else if (y == 5) { src = w1; dst = d1; }
    else if (y == 6) { src = w2; dst = d2; }
    else            { src = w3; dst = d3; }
    const int n8 = (int)(WNE / 8);            // all segments are 1M f32
    int i = blockIdx.x * blockDim.x + threadIdx.x;
    int stride = gridDim.x * blockDim.x;
    for (; i < n8; i += stride) {
        float4v a = ((const float4v*)src)[2 * i];
        float4v b = ((const float4v*)src)[2 * i + 1];
        u32x4 o;
        o[0] = cvt_pk_bf16(a[0] * sc, a[1] * sc);
        o[1] = cvt_pk_bf16(a[2] * sc, a[3] * sc);
        o[2] = cvt_pk_bf16(b[0] * sc, b[1] * sc);
        o[3] = cvt_pk_bf16(b[2] * sc, b[3] * sc);
        ((u32x4*)dst)[i] = o;
    }
}

// ----------------- GEMM, dbuf + single barrier per K-step ------------------
// 128x128 tile, BK=32, K=1024, 256 thr (4 waves 2x2). Stage(next) issued
// BEFORE compute(cur); one __syncthreads per K-step.
// MODE 0 (fused, grid 768): id<512 -> z=id>>8 Q/K proj (col-bias, bf16 out,
//   Wq path pre-scaled); id>=512 -> V^T gemm: C = Wv . x_b^T (row-bias bv),
//   out row-major [1024 hd][2048 t] at vt + b*1024*2048 (coalesced in t).
// MODE 1 (grid 256): out-proj, f32 out + col-bias.
template<int MODE>
__global__ __launch_bounds__(256) void gemm2(const u16* __restrict__ xb,
        const u16* __restrict__ Wb, const float* __restrict__ bq,
        const float* __restrict__ bk, const float* __restrict__ bvv,
        u16* __restrict__ outq, u16* __restrict__ vt, float* __restrict__ outf) {
    __shared__ alignas(16) u16 As[2][128 * 32];
    __shared__ alignas(16) u16 Bs[2][128 * 32];

    const int tid  = threadIdx.x;
    const int wave = tid >> 6, lane = tid & 63;
    const int lr = lane & 15, lg = lane >> 4;
    const int wr = wave >> 1, wc = wave & 1;
    const int K = 1024;

    const u16 *Ap, *Wp;
    int m0, n0, zb = 0;
    bool vtmode = false;
    const int id = blockIdx.x;
    if (MODE == 0) {
        if (id < 512) {
            zb = id >> 8; int r = id & 255;
            m0 = (r >> 3) * 128; n0 = (r & 7) * 128;
            Ap = xb; Wp = Wb + (size_t)zb * WNE;
        } else {
            int v = id - 512; zb = v >> 7; int r = v & 127;
            m0 = (r >> 4) * 128; n0 = (r & 15) * 128;
            Ap = Wb + 2 * WNE;                       // Wv
            Wp = xb + (size_t)zb * 2048 * 1024;      // x_b
            vtmode = true;
        }
    } else {
        m0 = (id >> 3) * 128; n0 = (id & 7) * 128;
        Ap = xb; Wp = Wb;
    }

    f32x4 acc[4][4];
#pragma unroll
    for (int m = 0; m < 4; ++m)
#pragma unroll
        for (int n = 0; n < 4; ++n) acc[m][n] = (f32x4){0.f, 0.f, 0.f, 0.f};

#define G_STAGE(BB_, KK_)                                                     \
    {                                                                         \
        _Pragma("unroll")                                                     \
        for (int it = 0; it < 2; ++it) {                                      \
            int c = it * 256 + tid;                                           \
            int row = c >> 2, cc = (c & 3) * 8;                               \
            load_lds16(Ap + (size_t)(m0 + row) * K + (KK_) + cc,              \
                       &As[BB_][(size_t)(it * 256 + wave * 64) * 8]);         \
            load_lds16(Wp + (size_t)(n0 + row) * K + (KK_) + cc,              \
                       &Bs[BB_][(size_t)(it * 256 + wave * 64) * 8]);         \
        }                                                                     \
    }

    G_STAGE(0, 0);
    __syncthreads();
    int cur = 0;
    for (int k0 = 0; k0 < K; k0 += 32) {
        if (k0 + 32 < K) G_STAGE(cur ^ 1, k0 + 32);

        bf16x8 af[4], bfm[4];
#pragma unroll
        for (int m = 0; m < 4; ++m)
            af[m] = *(const bf16x8*)&As[cur][(wr * 64 + m * 16 + lr) * 32 + lg * 8];
#pragma unroll
        for (int n = 0; n < 4; ++n)
            bfm[n] = *(const bf16x8*)&Bs[cur][(wc * 64 + n * 16 + lr) * 32 + lg * 8];
#pragma unroll
        for (int m = 0; m < 4; ++m)
#pragma unroll
            for (int n = 0; n < 4; ++n)
                acc[m][n] = mfma16(af[m], bfm[n], acc[m][n]);

        __syncthreads();   // drains vmcnt: next buffer published
        cur ^= 1;
    }
#undef G_STAGE

    if (MODE == 1) {
#pragma unroll
        for (int n = 0; n < 4; ++n) {
            int col = n0 + wc * 64 + n * 16 + lr;
            float bvl = bq[col];
#pragma unroll
            for (int m = 0; m < 4; ++m) {
                int row = m0 + wr * 64 + m * 16 + lg * 4;
#pragma unroll
                for (int r = 0; r < 4; ++r)
                    outf[(size_t)(row + r) * 1024 + col] = acc[m][n][r] + bvl;
            }
        }
    } else if (!vtmode) {
        const float* bias = zb ? bk : bq;
        const float bsc = zb ? 1.0f : CEXP;
#pragma unroll
        for (int n = 0; n < 4; ++n) {
            int col = n0 + wc * 64 + n * 16 + lr;
            float bvl = bias[col] * bsc;
#pragma unroll
            for (int m = 0; m < 4; ++m) {
                int row = m0 + wr * 64 + m * 16 + lg * 4;
#pragma unroll
                for (int r = 0; r < 4; ++r)
                    outq[(size_t)zb * XNE + (size_t)(row + r) * 1024 + col] =
                        f2bf(acc[m][n][r] + bvl);
            }
        }
    } else {
        // V^T: rows = hd (row-bias), cols = t (coalesced)
        u16* vo = vt + (size_t)zb * 1024 * 2048;
#pragma unroll
        for (int m = 0; m < 4; ++m) {
            int rowb = m0 + wr * 64 + m * 16 + lg * 4;
            float bvr[4];
#pragma unroll
            for (int r = 0; r < 4; ++r) bvr[r] = bvv[rowb + r];
#pragma unroll
            for (int n = 0; n < 4; ++n) {
                int col = n0 + wc * 64 + n * 16 + lr;
#pragma unroll
                for (int r = 0; r < 4; ++r)
                    vo[(size_t)(rowb + r) * 2048 + col] = f2bf(acc[m][n][r] + bvr[r]);
            }
        }
    }
}

// --------------------------- attention pass 1 ------------------------------
// KV-split flash partials, base-free exp2 softmax (Q pre-scaled by CEXP).
// 512-key chunks: slot s -> (qi, ch) with nch(qi) = (qi>>2)+1 (40 slots/bh).
// Grid 1280 XCD-mapped, LONGEST-FIRST within XCD (s = 39 - raw -> big qi
// dispatch first; short blocks backfill the tail).
// 128-key LDS stage (32KB): one barrier pair covers two 64-key sub-tiles.
// l computed on the MFMA pipe: ol = mfma32(ones, pb, ol) makes every C row
// the key-sum of P -> l = ol[0] per lane, NO VALU tree / cross-lane shfl.
// No setprio (m190/r12: hurts lockstep waves). nc==1 (qi<4): write Y direct.
__global__ __launch_bounds__(256) void attn_part(const u16* __restrict__ Qb,
        const u16* __restrict__ Kb, const u16* __restrict__ VTb,
        u16* __restrict__ Op, float* __restrict__ Ml, u16* __restrict__ Yb) {
    __shared__ alignas(16) u16 Ks[128 * 64];  // [key][d], XOR-swizzled 16B slots
    __shared__ alignas(16) u16 Vs[64 * 128];  // [d][key], XOR-swizzled 16B slots

    const int tid  = threadIdx.x;
    const int wave = tid >> 6, lane = tid & 63;
    const int lq = lane & 31, hi = lane >> 5;

    const int i0 = blockIdx.x;
    const int bh = (i0 & 7) * 4 + ((i0 >> 3) / 40);
    const int s  = 39 - ((i0 >> 3) % 40);     // longest-first
    int qi = 0, ch = 0;
    {
        int cum = 0, found = 0;
#pragma unroll
        for (int j = 0; j < 16; ++j) {
            int n = (j >> 2) + 1;
            if (!found && s < cum + n) { qi = j; ch = s - cum; found = 1; }
            cum += n;
        }
    }
    const int nc = (qi >> 2) + 1;
    const int b = bh >> 4, h = bh & 15;
    const size_t rb = (size_t)b * TT;
    const int hoff = h * DH;
    const int q0w = qi * 128 + wave * 32;     // warp q base
    const int k0 = ch * 512;
    const int kend = qi * 128 + 128;          // multiple of 128
    const int k1 = (k0 + 512 < kend) ? k0 + 512 : kend;

    const u16* Kbh = Kb + rb * DD + hoff;
    const u16* Vbh = VTb + (size_t)bh * 64 * 2048;

    // Q fragments (B-operand): col=lane&31=q, k=(lane>>5)*8+j ; 4 chunks of 16
    bf16x8 qf[4];
    {
        const u16* qrow = Qb + (rb + q0w + lq) * DD + hoff + hi * 8;
#pragma unroll
        for (int kc = 0; kc < 4; ++kc) qf[kc] = *(const bf16x8*)(qrow + kc * 16);
    }

    // all-ones A-operand (layout-invariant) for the l row-sum MFMA
    bf16x8 ones8;
    {
        u32x4 w; w[0] = w[1] = w[2] = w[3] = 0x3F803F80u;
        ones8 = __builtin_bit_cast(bf16x8, w);
    }

    f32x16 o0 = {}, o1 = {}, ol = {};
    const int rowm = lq & 7;

    for (int kv0 = k0; kv0 < k1; kv0 += 128) {
        __syncthreads();
        // stage K [128 key][64 d] (8 slots/row) and V^T [64 d][128 key]
        // (16 slots/row); source pre-swizzled, LDS linear (rule 21)
#pragma unroll
        for (int it = 0; it < 4; ++it) {
            int c = it * 256 + tid;
            int krow = c >> 3, ksl = c & 7;
            load_lds16(Kbh + (size_t)(kv0 + krow) * DD + ((ksl ^ (krow & 7)) * 8),
                       &Ks[(size_t)(it * 256 + wave * 64) * 8]);
        }
#pragma unroll
        for (int it = 0; it < 4; ++it) {
            int c = it * 256 + tid;
            int vrow = c >> 4, vsl = c & 15;
            load_lds16(Vbh + (size_t)vrow * 2048 + kv0 + ((vsl ^ (vrow & 7)) * 8),
                       &Vs[(size_t)(it * 256 + wave * 64) * 8]);
        }
        __syncthreads();

#pragma unroll
        for (int sub = 0; sub < 2; ++sub) {
            const int kb = kv0 + sub * 64;
            if (kb < q0w + 32) {
                const bool diag = (kb + 63 > q0w);
                const int qrel = q0w + lq - kb;
                bf16x8 pb[4];

                // ---- keys kb+0..31
                {
                    f32x16 st = {};
#pragma unroll
                    for (int kc = 0; kc < 4; ++kc) {
                        bf16x8 kf = *(const bf16x8*)&Ks[(sub * 64 + lq) * 64 +
                                                        ((2 * kc + hi) ^ rowm) * 8];
                        st = mfma32(kf, qf[kc], st);
                    }
                    if (diag) {
#pragma unroll
                        for (int r = 0; r < 16; ++r) {
                            int key = (r & 3) + 8 * (r >> 2) + 4 * hi;
                            if (key > qrel) st[r] = -1e30f;
                        }
                    }
#pragma unroll
                    for (int r = 0; r < 16; ++r) st[r] = __builtin_amdgcn_exp2f(st[r]);
                    pb[0] = pack8(st[0], st[1], st[2], st[3], st[4], st[5], st[6], st[7]);
                    pb[1] = pack8(st[8], st[9], st[10], st[11], st[12], st[13], st[14], st[15]);
                }
                // ---- keys kb+32..63
                {
                    f32x16 st = {};
#pragma unroll
                    for (int kc = 0; kc < 4; ++kc) {
                        bf16x8 kf = *(const bf16x8*)&Ks[(sub * 64 + 32 + lq) * 64 +
                                                        ((2 * kc + hi) ^ rowm) * 8];
                        st = mfma32(kf, qf[kc], st);
                    }
                    if (diag) {
#pragma unroll
                        for (int r = 0; r < 16; ++r) {
                            int key = 32 + (r & 3) + 8 * (r >> 2) + 4 * hi;
                            if (key > qrel) st[r] = -1e30f;
                        }
                    }
#pragma unroll
                    for (int r = 0; r < 16; ++r) st[r] = __builtin_amdgcn_exp2f(st[r]);
                    pb[2] = pack8(st[0], st[1], st[2], st[3], st[4], st[5], st[6], st[7]);
                    pb[3] = pack8(st[8], st[9], st[10], st[11], st[12], st[13], st[14], st[15]);
                }

                // O^T += V^T . P^T ; l accumulated on the MFMA pipe (ones row)
#pragma unroll
                for (int ks = 0; ks < 4; ++ks) {
                    bf16x8 vf0 = *(const bf16x8*)&Vs[lq * 128 +
                                    (sub * 8 + ((ks * 2 + hi) ^ rowm)) * 8];
                    bf16x8 vf1 = *(const bf16x8*)&Vs[(32 + lq) * 128 +
                                    (sub * 8 + ((ks * 2 + hi) ^ rowm)) * 8];
                    o0 = mfma32(vf0, pb[ks], o0);
                    o1 = mfma32(vf1, pb[ks], o1);
                    ol = mfma32(ones8, pb[ks], ol);
                }
            }
        }
    }

    const float l_i = ol[0];                  // every C row holds the key-sum
    const int col = wave * 32 + lq;

    if (nc == 1) {
        // single chunk: normalize and write Y directly
        const float inv = 1.0f / l_i;
        u16* yrow = Yb + (rb + q0w + lq) * DD + hoff;
#pragma unroll
        for (int g = 0; g < 4; ++g) {
            u16x4 p0, p1;
#pragma unroll
            for (int j = 0; j < 4; ++j) {
                p0[j] = f2bf(o0[4 * g + j] * inv);
                p1[j] = f2bf(o1[4 * g + j] * inv);
            }
            *(u16x4*)&yrow[8 * g + 4 * hi]      = p0;
            *(u16x4*)&yrow[32 + 8 * g + 4 * hi] = p1;
        }
    } else {
        const int slot = bh * 40 + s;
        u16* op = Op + (size_t)slot * 8192;
#pragma unroll
        for (int r = 0; r < 16; ++r) {
            const int d0 = (r & 3) + 8 * (r >> 2) + 4 * hi;
            op[d0 * 128 + col]        = f2bf(o0[r]);
            op[(32 + d0) * 128 + col] = f2bf(o1[r]);
        }
        if (hi == 0) Ml[(size_t)slot * 128 + col] = l_i;
    }
}

// --------------------------- attention pass 2 ------------------------------
// grid 384 = 32 bh x 12 qi (qi>=4 only; qi<4 written by pass1); 256 thr.
// O = sum_c O_c / sum_c l_c (common exp2 base, no max bookkeeping).
__global__ __launch_bounds__(256) void attn_merge(const u16* __restrict__ Op,
        const float* __restrict__ Ml, u16* __restrict__ Yb) {
    const int bq = blockIdx.x;
    const int bh = bq / 12, qi = (bq % 12) + 4;
    const int nc = (qi >> 2) + 1;
    int cum = 0;
#pragma unroll
    for (int j = 0; j < 16; ++j) cum += (j < qi) ? ((j >> 2) + 1) : 0;
    const int s0 = bh * 40 + cum;

    const int t = threadIdx.x;
    const int row = t >> 1, dh = (t & 1) * 32;

    float L = 0.f;
    float acc[32];
#pragma unroll
    for (int d = 0; d < 32; ++d) acc[d] = 0.f;
#pragma unroll
    for (int c = 0; c < 4; ++c) {
        if (c < nc) {
            L += Ml[(size_t)(s0 + c) * 128 + row];
            const u16* op = Op + (size_t)(s0 + c) * 8192 + row;
#pragma unroll
            for (int d = 0; d < 32; ++d)
                acc[d] += bf2f(op[(dh + d) * 128]);
        }
    }
    const float inv = 1.0f / L;

    const int b = bh >> 4, h = bh & 15;
    u16* yrow = Yb + ((size_t)(b * TT + qi * 128 + row)) * DD + h * DH + dh;
#pragma unroll
    for (int g = 0; g < 8; ++g) {
        u16x4 p;
#pragma unroll
        for (int j = 0; j < 4; ++j) p[j] = f2bf(acc[4 * g + j] * inv);
        *(u16x4*)&yrow[4 * g] = p;
    }
}

// ------------------------------- launcher ----------------------------------
extern "C" void kernel_launch(void* const* d_in, const int* in_sizes, int n_in,
                              void* d_out, int out_size, void* d_ws, size_t ws_size,
                              hipStream_t stream) {
    const float* x  = (const float*)d_in[0];
    const float* Wq = (const float*)d_in[1];
    const float* bq = (const float*)d_in[2];
    const float* Wk = (const float*)d_in[3];
    const float* bk = (const float*)d_in[4];
    const float* Wv = (const float*)d_in[5];
    const float* bv = (const float*)d_in[6];
    const float* Wo = (const float*)d_in[7];
    const float* bo = (const float*)d_in[8];
    float* out = (float*)d_out;

    u16* xb  = (u16*)d_ws;
    u16* Wb  = xb  + XNE;         // Wq,Wk,Wv stacked: 3*WNE
    u16* Wob = Wb  + 3 * WNE;
    u16* QKV = Wob + WNE;         // Q, K, VT stacked: 3*XNE
    u16* Yb  = QKV + 3 * XNE;
    u16* Op  = Yb  + XNE;                             // bf16 [1280][64][128]
    float* Ml = (float*)(Op + (size_t)NSLOT * 8192);  // f32 [1280][128]

    // all fp32->bf16 conversions in one launch
    cvt5_kernel<<<dim3(128, 8), 256, 0, stream>>>(x, Wq, Wk, Wv, Wo,
            xb, Wb, Wb + WNE, Wb + 2 * WNE, Wob);

    // fused Q-proj, K-proj, V^T gemm (768 blocks)
    gemm2<0><<<768, 256, 0, stream>>>(xb, Wb, bq, bk, bv,
                                      QKV, QKV + 2 * XNE, nullptr);
    attn_part<<<NSLOT, 256, 0, stream>>>(QKV, QKV + XNE, QKV + 2 * XNE,
                                         Op, Ml, Yb);
    attn_merge<<<384, 256, 0, stream>>>(Op, Ml, Yb);
    // out-proj (f32 out + bias)
    gemm2<1><<<256, 256, 0, stream>>>(Yb, Wob, bo, nullptr, nullptr,
                                      nullptr, nullptr, out);
}

// Round 16
// 113.859 us; speedup vs baseline: 1.1246x; 1.0032x over previous
//
#include <hip/hip_runtime.h>
#include <stdint.h>

// ---------------------------------------------------------------------------
// CausalSelfAttention (B=2, T=2048, D=1024, H=16, Dh=64), fp32 in/out.
// cvt5 (one launch, Wq pre-scaled) -> fused {Q,K proj + V^T} gemm (dbuf,
// 1 barrier/K-step) -> flash attn KV-split (512-key chunks, 128-key LDS
// stage, longest-first) -> merge -> out gemm.
// ---------------------------------------------------------------------------

typedef unsigned short u16;
typedef __attribute__((ext_vector_type(8)))  __bf16 bf16x8;   // 4 VGPR MFMA A/B frag
typedef __attribute__((ext_vector_type(4)))  float  f32x4;    // 16x16 C/D frag
typedef __attribute__((ext_vector_type(16))) float  f32x16;   // 32x32 C/D frag
typedef __attribute__((ext_vector_type(4)))  float  float4v;
typedef __attribute__((ext_vector_type(4)))  unsigned short u16x4;
typedef __attribute__((ext_vector_type(4)))  unsigned int   u32x4;
typedef __attribute__((ext_vector_type(8)))  short  short8;   // raw 16B load

#define BB 2
#define TT 2048
#define DD 1024
#define HH 16
#define DH 64
#define MM (BB*TT)          // 4096 rows
#define NSLOT 1280          // 32 bh * 40 (qi,chunk) slots (512-key chunks)
#define CEXP 0.18033688011f // 0.125 * log2(e), folded into Wq/bq
#define XNE ((size_t)MM*DD)
#define WNE ((size_t)DD*DD)

static __device__ __forceinline__ u16 f2bf(float f) {
    uint32_t u = __builtin_bit_cast(uint32_t, f);
    u += 0x7FFFu + ((u >> 16) & 1u);          // round-to-nearest-even
    return (u16)(u >> 16);
}
static __device__ __forceinline__ float bf2f(u16 v) {
    uint32_t u = (uint32_t)v << 16;
    return __builtin_bit_cast(float, u);
}

static __device__ __forceinline__ unsigned cvt_pk_bf16(float a, float b) {
    unsigned r;
    asm("v_cvt_pk_bf16_f32 %0, %1, %2" : "=v"(r) : "v"(a), "v"(b));
    return r;
}

// global(16B per lane) -> LDS direct copy (wave-uniform dst base + lane*16).
static __device__ __forceinline__ void load_lds16(const u16* g, const u16* lds_base) {
    __builtin_amdgcn_global_load_lds(
        (const __attribute__((address_space(1))) void*)(uintptr_t)g,
        (__attribute__((address_space(3)))  void*)(uint32_t)(uintptr_t)lds_base,
        16u, 0, 0u);
}

static __device__ __forceinline__ f32x4 mfma16(bf16x8 a, bf16x8 b, f32x4 c) {
    return __builtin_amdgcn_mfma_f32_16x16x32_bf16(a, b, c, 0, 0, 0);
}
static __device__ __forceinline__ f32x16 mfma32(bf16x8 a, bf16x8 b, f32x16 c) {
    return __builtin_amdgcn_mfma_f32_32x32x16_bf16(a, b, c, 0, 0, 0);
}

// sum of all 16 regs (15-add tree)
static __device__ __forceinline__ float tree_sum16(const f32x16& a) {
    float m[8];
#pragma unroll
    for (int r = 0; r < 8; ++r) m[r] = a[r] + a[r + 8];
#pragma unroll
    for (int off = 4; off; off >>= 1)
#pragma unroll
        for (int r = 0; r < off; ++r) m[r] += m[r + off];
    return m[0];
}

// P regs (8 f32, C-layout key groups) -> one B-operand bf16x8 (T12)
static __device__ __forceinline__ bf16x8 pack8(float s0, float s1, float s2,
        float s3, float s4, float s5, float s6, float s7) {
    unsigned c0 = cvt_pk_bf16(s0, s1);
    unsigned c1 = cvt_pk_bf16(s2, s3);
    unsigned c2 = cvt_pk_bf16(s4, s5);
    unsigned c3 = cvt_pk_bf16(s6, s7);
    asm volatile("v_permlane32_swap_b32 %0, %1" : "+v"(c0), "+v"(c2));
    asm volatile("v_permlane32_swap_b32 %0, %1" : "+v"(c1), "+v"(c3));
    u32x4 w; w[0] = c0; w[1] = c1; w[2] = c2; w[3] = c3;
    return __builtin_bit_cast(bf16x8, w);
}

// ------------- fp32 -> bf16, ALL tensors in one launch (cvt_pk) ------------
// grid (128, 8): y<4 -> quarter y of x; y>=4 -> weight y-4 (Wq scaled).
__global__ __launch_bounds__(256) void cvt5_kernel(const float* __restrict__ x,
        const float* __restrict__ w0, const float* __restrict__ w1,
        const float* __restrict__ w2, const float* __restrict__ w3,
        u16* __restrict__ xd, u16* __restrict__ d0, u16* __restrict__ d1,
        u16* __restrict__ d2, u16* __restrict__ d3) {
    const int y = blockIdx.y;
    const float* src;
    u16* dst;
    float sc = 1.0f;
    if (y < 4) { src = x + (size_t)y * (XNE / 4); dst = xd + (size_t)y * (XNE / 4); }
    else if (y == 4) { src = w0; dst = d0; sc = CEXP; }
    else if (y == 5) { src = w1; dst = d1; }
    else if (y == 6) { src = w2; dst = d2; }
    else            { src = w3; dst = d3; }
    const int n8 = (int)(WNE / 8);            // all segments are 1M f32
    int i = blockIdx.x * blockDim.x + threadIdx.x;
    int stride = gridDim.x * blockDim.x;
    for (; i < n8; i += stride) {
        float4v a = ((const float4v*)src)[2 * i];
        float4v b = ((const float4v*)src)[2 * i + 1];
        u32x4 o;
        o[0] = cvt_pk_bf16(a[0] * sc, a[1] * sc);
        o[1] = cvt_pk_bf16(a[2] * sc, a[3] * sc);
        o[2] = cvt_pk_bf16(b[0] * sc, b[1] * sc);
        o[3] = cvt_pk_bf16(b[2] * sc, b[3] * sc);
        ((u32x4*)dst)[i] = o;
    }
}

// ----------------- GEMM, dbuf + single barrier per K-step ------------------
// 128x128 tile, BK=32, K=1024, 256 thr (4 waves 2x2). Stage(next) issued
// BEFORE compute(cur); one __syncthreads per K-step.
// MODE 0 (fused, grid 768): id<512 -> z=id>>8 Q/K proj (col-bias, bf16 out,
//   Wq path pre-scaled); id>=512 -> V^T gemm: C = Wv . x_b^T (row-bias bv),
//   out row-major [1024 hd][2048 t] at vt + b*1024*2048 (coalesced in t).
// MODE 1 (grid 256): out-proj, f32 out + col-bias.
template<int MODE>
__global__ __launch_bounds__(256) void gemm2(const u16* __restrict__ xb,
        const u16* __restrict__ Wb, const float* __restrict__ bq,
        const float* __restrict__ bk, const float* __restrict__ bvv,
        u16* __restrict__ outq, u16* __restrict__ vt, float* __restrict__ outf) {
    __shared__ alignas(16) u16 As[2][128 * 32];
    __shared__ alignas(16) u16 Bs[2][128 * 32];

    const int tid  = threadIdx.x;
    const int wave = tid >> 6, lane = tid & 63;
    const int lr = lane & 15, lg = lane >> 4;
    const int wr = wave >> 1, wc = wave & 1;
    const int K = 1024;

    const u16 *Ap, *Wp;
    int m0, n0, zb = 0;
    bool vtmode = false;
    const int id = blockIdx.x;
    if (MODE == 0) {
        if (id < 512) {
            zb = id >> 8; int r = id & 255;
            m0 = (r >> 3) * 128; n0 = (r & 7) * 128;
            Ap = xb; Wp = Wb + (size_t)zb * WNE;
        } else {
            int v = id - 512; zb = v >> 7; int r = v & 127;
            m0 = (r >> 4) * 128; n0 = (r & 15) * 128;
            Ap = Wb + 2 * WNE;                       // Wv
            Wp = xb + (size_t)zb * 2048 * 1024;      // x_b
            vtmode = true;
        }
    } else {
        m0 = (id >> 3) * 128; n0 = (id & 7) * 128;
        Ap = xb; Wp = Wb;
    }

    f32x4 acc[4][4];
#pragma unroll
    for (int m = 0; m < 4; ++m)
#pragma unroll
        for (int n = 0; n < 4; ++n) acc[m][n] = (f32x4){0.f, 0.f, 0.f, 0.f};

#define G_STAGE(BB_, KK_)                                                     \
    {                                                                         \
        _Pragma("unroll")                                                     \
        for (int it = 0; it < 2; ++it) {                                      \
            int c = it * 256 + tid;                                           \
            int row = c >> 2, cc = (c & 3) * 8;                               \
            load_lds16(Ap + (size_t)(m0 + row) * K + (KK_) + cc,              \
                       &As[BB_][(size_t)(it * 256 + wave * 64) * 8]);         \
            load_lds16(Wp + (size_t)(n0 + row) * K + (KK_) + cc,              \
                       &Bs[BB_][(size_t)(it * 256 + wave * 64) * 8]);         \
        }                                                                     \
    }

    G_STAGE(0, 0);
    __syncthreads();
    int cur = 0;
    for (int k0 = 0; k0 < K; k0 += 32) {
        if (k0 + 32 < K) G_STAGE(cur ^ 1, k0 + 32);

        bf16x8 af[4], bfm[4];
#pragma unroll
        for (int m = 0; m < 4; ++m)
            af[m] = *(const bf16x8*)&As[cur][(wr * 64 + m * 16 + lr) * 32 + lg * 8];
#pragma unroll
        for (int n = 0; n < 4; ++n)
            bfm[n] = *(const bf16x8*)&Bs[cur][(wc * 64 + n * 16 + lr) * 32 + lg * 8];
#pragma unroll
        for (int m = 0; m < 4; ++m)
#pragma unroll
            for (int n = 0; n < 4; ++n)
                acc[m][n] = mfma16(af[m], bfm[n], acc[m][n]);

        __syncthreads();   // drains vmcnt: next buffer published
        cur ^= 1;
    }
#undef G_STAGE

    if (MODE == 1) {
#pragma unroll
        for (int n = 0; n < 4; ++n) {
            int col = n0 + wc * 64 + n * 16 + lr;
            float bvl = bq[col];
#pragma unroll
            for (int m = 0; m < 4; ++m) {
                int row = m0 + wr * 64 + m * 16 + lg * 4;
#pragma unroll
                for (int r = 0; r < 4; ++r)
                    outf[(size_t)(row + r) * 1024 + col] = acc[m][n][r] + bvl;
            }
        }
    } else if (!vtmode) {
        const float* bias = zb ? bk : bq;
        const float bsc = zb ? 1.0f : CEXP;
#pragma unroll
        for (int n = 0; n < 4; ++n) {
            int col = n0 + wc * 64 + n * 16 + lr;
            float bvl = bias[col] * bsc;
#pragma unroll
            for (int m = 0; m < 4; ++m) {
                int row = m0 + wr * 64 + m * 16 + lg * 4;
#pragma unroll
                for (int r = 0; r < 4; ++r)
                    outq[(size_t)zb * XNE + (size_t)(row + r) * 1024 + col] =
                        f2bf(acc[m][n][r] + bvl);
            }
        }
    } else {
        // V^T: rows = hd (row-bias), cols = t (coalesced)
        u16* vo = vt + (size_t)zb * 1024 * 2048;
#pragma unroll
        for (int m = 0; m < 4; ++m) {
            int rowb = m0 + wr * 64 + m * 16 + lg * 4;
            float bvr[4];
#pragma unroll
            for (int r = 0; r < 4; ++r) bvr[r] = bvv[rowb + r];
#pragma unroll
            for (int n = 0; n < 4; ++n) {
                int col = n0 + wc * 64 + n * 16 + lr;
#pragma unroll
                for (int r = 0; r < 4; ++r)
                    vo[(size_t)(rowb + r) * 2048 + col] = f2bf(acc[m][n][r] + bvr[r]);
            }
        }
    }
}

// --------------------------- attention pass 1 ------------------------------
// KV-split flash partials, base-free exp2 softmax (Q pre-scaled by CEXP).
// 512-key chunks: slot s -> (qi, ch) with nch(qi) = (qi>>2)+1 (40 slots/bh).
// Grid 1280 XCD-mapped, LONGEST-FIRST within XCD (s = 39 - raw).
// 128-key LDS stage (32KB): one barrier pair covers two 64-key sub-tiles.
// l via VALU tree (r15's ones-MFMA variant cost +16 VGPR and regressed).
// No setprio (m190/r12: hurts lockstep waves). nc==1 (qi<4): write Y direct.
__global__ __launch_bounds__(256) void attn_part(const u16* __restrict__ Qb,
        const u16* __restrict__ Kb, const u16* __restrict__ VTb,
        u16* __restrict__ Op, float* __restrict__ Ml, u16* __restrict__ Yb) {
    __shared__ alignas(16) u16 Ks[128 * 64];  // [key][d], XOR-swizzled 16B slots
    __shared__ alignas(16) u16 Vs[64 * 128];  // [d][key], XOR-swizzled 16B slots

    const int tid  = threadIdx.x;
    const int wave = tid >> 6, lane = tid & 63;
    const int lq = lane & 31, hi = lane >> 5;

    const int i0 = blockIdx.x;
    const int bh = (i0 & 7) * 4 + ((i0 >> 3) / 40);
    const int s  = 39 - ((i0 >> 3) % 40);     // longest-first
    int qi = 0, ch = 0;
    {
        int cum = 0, found = 0;
#pragma unroll
        for (int j = 0; j < 16; ++j) {
            int n = (j >> 2) + 1;
            if (!found && s < cum + n) { qi = j; ch = s - cum; found = 1; }
            cum += n;
        }
    }
    const int nc = (qi >> 2) + 1;
    const int b = bh >> 4, h = bh & 15;
    const size_t rb = (size_t)b * TT;
    const int hoff = h * DH;
    const int q0w = qi * 128 + wave * 32;     // warp q base
    const int k0 = ch * 512;
    const int kend = qi * 128 + 128;          // multiple of 128
    const int k1 = (k0 + 512 < kend) ? k0 + 512 : kend;

    const u16* Kbh = Kb + rb * DD + hoff;
    const u16* Vbh = VTb + (size_t)bh * 64 * 2048;

    // Q fragments (B-operand): col=lane&31=q, k=(lane>>5)*8+j ; 4 chunks of 16
    bf16x8 qf[4];
    {
        const u16* qrow = Qb + (rb + q0w + lq) * DD + hoff + hi * 8;
#pragma unroll
        for (int kc = 0; kc < 4; ++kc) qf[kc] = *(const bf16x8*)(qrow + kc * 16);
    }

    f32x16 o0 = {}, o1 = {};
    float l_i = 0.f;
    const int rowm = lq & 7;

    for (int kv0 = k0; kv0 < k1; kv0 += 128) {
        __syncthreads();
        // stage K [128 key][64 d] (8 slots/row) and V^T [64 d][128 key]
        // (16 slots/row); source pre-swizzled, LDS linear (rule 21)
#pragma unroll
        for (int it = 0; it < 4; ++it) {
            int c = it * 256 + tid;
            int krow = c >> 3, ksl = c & 7;
            load_lds16(Kbh + (size_t)(kv0 + krow) * DD + ((ksl ^ (krow & 7)) * 8),
                       &Ks[(size_t)(it * 256 + wave * 64) * 8]);
        }
#pragma unroll
        for (int it = 0; it < 4; ++it) {
            int c = it * 256 + tid;
            int vrow = c >> 4, vsl = c & 15;
            load_lds16(Vbh + (size_t)vrow * 2048 + kv0 + ((vsl ^ (vrow & 7)) * 8),
                       &Vs[(size_t)(it * 256 + wave * 64) * 8]);
        }
        __syncthreads();

#pragma unroll
        for (int sub = 0; sub < 2; ++sub) {
            const int kb = kv0 + sub * 64;
            if (kb < q0w + 32) {
                const bool diag = (kb + 63 > q0w);
                const int qrel = q0w + lq - kb;
                bf16x8 pb[4];

                // ---- keys kb+0..31
                {
                    f32x16 st = {};
#pragma unroll
                    for (int kc = 0; kc < 4; ++kc) {
                        bf16x8 kf = *(const bf16x8*)&Ks[(sub * 64 + lq) * 64 +
                                                        ((2 * kc + hi) ^ rowm) * 8];
                        st = mfma32(kf, qf[kc], st);
                    }
                    if (diag) {
#pragma unroll
                        for (int r = 0; r < 16; ++r) {
                            int key = (r & 3) + 8 * (r >> 2) + 4 * hi;
                            if (key > qrel) st[r] = -1e30f;
                        }
                    }
#pragma unroll
                    for (int r = 0; r < 16; ++r) st[r] = __builtin_amdgcn_exp2f(st[r]);
                    l_i += tree_sum16(st);
                    pb[0] = pack8(st[0], st[1], st[2], st[3], st[4], st[5], st[6], st[7]);
                    pb[1] = pack8(st[8], st[9], st[10], st[11], st[12], st[13], st[14], st[15]);
                }
                // ---- keys kb+32..63
                {
                    f32x16 st = {};
#pragma unroll
                    for (int kc = 0; kc < 4; ++kc) {
                        bf16x8 kf = *(const bf16x8*)&Ks[(sub * 64 + 32 + lq) * 64 +
                                                        ((2 * kc + hi) ^ rowm) * 8];
                        st = mfma32(kf, qf[kc], st);
                    }
                    if (diag) {
#pragma unroll
                        for (int r = 0; r < 16; ++r) {
                            int key = 32 + (r & 3) + 8 * (r >> 2) + 4 * hi;
                            if (key > qrel) st[r] = -1e30f;
                        }
                    }
#pragma unroll
                    for (int r = 0; r < 16; ++r) st[r] = __builtin_amdgcn_exp2f(st[r]);
                    l_i += tree_sum16(st);
                    pb[2] = pack8(st[0], st[1], st[2], st[3], st[4], st[5], st[6], st[7]);
                    pb[3] = pack8(st[8], st[9], st[10], st[11], st[12], st[13], st[14], st[15]);
                }

                // O^T += V^T . P^T : A=V^T (row=d, swizzled read), B=P^T
#pragma unroll
                for (int ks = 0; ks < 4; ++ks) {
                    bf16x8 vf0 = *(const bf16x8*)&Vs[lq * 128 +
                                    (sub * 8 + ((ks * 2 + hi) ^ rowm)) * 8];
                    bf16x8 vf1 = *(const bf16x8*)&Vs[(32 + lq) * 128 +
                                    (sub * 8 + ((ks * 2 + hi) ^ rowm)) * 8];
                    o0 = mfma32(vf0, pb[ks], o0);
                    o1 = mfma32(vf1, pb[ks], o1);
                }
            }
        }
    }

    l_i += __shfl_xor(l_i, 32);
    const int col = wave * 32 + lq;

    if (nc == 1) {
        // single chunk: normalize and write Y directly
        const float inv = 1.0f / l_i;
        u16* yrow = Yb + (rb + q0w + lq) * DD + hoff;
#pragma unroll
        for (int g = 0; g < 4; ++g) {
            u16x4 p0, p1;
#pragma unroll
            for (int j = 0; j < 4; ++j) {
                p0[j] = f2bf(o0[4 * g + j] * inv);
                p1[j] = f2bf(o1[4 * g + j] * inv);
            }
            *(u16x4*)&yrow[8 * g + 4 * hi]      = p0;
            *(u16x4*)&yrow[32 + 8 * g + 4 * hi] = p1;
        }
    } else {
        const int slot = bh * 40 + s;
        u16* op = Op + (size_t)slot * 8192;
#pragma unroll
        for (int r = 0; r < 16; ++r) {
            const int d0 = (r & 3) + 8 * (r >> 2) + 4 * hi;
            op[d0 * 128 + col]        = f2bf(o0[r]);
            op[(32 + d0) * 128 + col] = f2bf(o1[r]);
        }
        if (hi == 0) Ml[(size_t)slot * 128 + col] = l_i;
    }
}

// --------------------------- attention pass 2 ------------------------------
// grid 384 = 32 bh x 12 qi (qi>=4 only; qi<4 written by pass1); 256 thr.
// O = sum_c O_c / sum_c l_c (common exp2 base, no max bookkeeping).
__global__ __launch_bounds__(256) void attn_merge(const u16* __restrict__ Op,
        const float* __restrict__ Ml, u16* __restrict__ Yb) {
    const int bq = blockIdx.x;
    const int bh = bq / 12, qi = (bq % 12) + 4;
    const int nc = (qi >> 2) + 1;
    int cum = 0;
#pragma unroll
    for (int j = 0; j < 16; ++j) cum += (j < qi) ? ((j >> 2) + 1) : 0;
    const int s0 = bh * 40 + cum;

    const int t = threadIdx.x;
    const int row = t >> 1, dh = (t & 1) * 32;

    float L = 0.f;
    float acc[32];
#pragma unroll
    for (int d = 0; d < 32; ++d) acc[d] = 0.f;
#pragma unroll
    for (int c = 0; c < 4; ++c) {
        if (c < nc) {
            L += Ml[(size_t)(s0 + c) * 128 + row];
            const u16* op = Op + (size_t)(s0 + c) * 8192 + row;
#pragma unroll
            for (int d = 0; d < 32; ++d)
                acc[d] += bf2f(op[(dh + d) * 128]);
        }
    }
    const float inv = 1.0f / L;

    const int b = bh >> 4, h = bh & 15;
    u16* yrow = Yb + ((size_t)(b * TT + qi * 128 + row)) * DD + h * DH + dh;
#pragma unroll
    for (int g = 0; g < 8; ++g) {
        u16x4 p;
#pragma unroll
        for (int j = 0; j < 4; ++j) p[j] = f2bf(acc[4 * g + j] * inv);
        *(u16x4*)&yrow[4 * g] = p;
    }
}

// ------------------------------- launcher ----------------------------------
extern "C" void kernel_launch(void* const* d_in, const int* in_sizes, int n_in,
                              void* d_out, int out_size, void* d_ws, size_t ws_size,
                              hipStream_t stream) {
    const float* x  = (const float*)d_in[0];
    const float* Wq = (const float*)d_in[1];
    const float* bq = (const float*)d_in[2];
    const float* Wk = (const float*)d_in[3];
    const float* bk = (const float*)d_in[4];
    const float* Wv = (const float*)d_in[5];
    const float* bv = (const float*)d_in[6];
    const float* Wo = (const float*)d_in[7];
    const float* bo = (const float*)d_in[8];
    float* out = (float*)d_out;

    u16* xb  = (u16*)d_ws;
    u16* Wb  = xb  + XNE;         // Wq,Wk,Wv stacked: 3*WNE
    u16* Wob = Wb  + 3 * WNE;
    u16* QKV = Wob + WNE;         // Q, K, VT stacked: 3*XNE
    u16* Yb  = QKV + 3 * XNE;
    u16* Op  = Yb  + XNE;                             // bf16 [1280][64][128]
    float* Ml = (float*)(Op + (size_t)NSLOT * 8192);  // f32 [1280][128]

    // all fp32->bf16 conversions in one launch
    cvt5_kernel<<<dim3(128, 8), 256, 0, stream>>>(x, Wq, Wk, Wv, Wo,
            xb, Wb, Wb + WNE, Wb + 2 * WNE, Wob);

    // fused Q-proj, K-proj, V^T gemm (768 blocks)
    gemm2<0><<<768, 256, 0, stream>>>(xb, Wb, bq, bk, bv,
                                      QKV, QKV + 2 * XNE, nullptr);
    attn_part<<<NSLOT, 256, 0, stream>>>(QKV, QKV + XNE, QKV + 2 * XNE,
                                         Op, Ml, Yb);
    attn_merge<<<384, 256, 0, stream>>>(Op, Ml, Yb);
    // out-proj (f32 out + bias)
    gemm2<1><<<256, 256, 0, stream>>>(Yb, Wob, bo, nullptr, nullptr,
                                      nullptr, nullptr, out);
}